// Round 2
// baseline (33420.316 us; speedup 1.0000x reference)
//
#include <hip/hip_runtime.h>
#include <math.h>

// OptNet IPM QP solve via Woodbury:
//  M = Q + G^T D G;  M^{-1} = Qi - Qi G^T (Dinv + K)^{-1} G Qi,  K = G Qi G^T
// Round 2: latency surgery. Register+shuffle 16x16 diag Cholesky (no LDS in the
// serial pivot chain), linv stored on the diagonal (divisions -> multiplies),
// register-prefetched tri-solve chains, 4-way accumulators in matvecs, rowOf LUT
// moved to global (LDS 49.6 -> ~41.8 KB).

__device__ __forceinline__ int ROFF(int i){ return (i*(i+1))>>1; }

__device__ __forceinline__ float waveReduceSum(float v){
  #pragma unroll
  for (int o=32;o>0;o>>=1) v += __shfl_down(v,o,64);
  return v;
}
__device__ __forceinline__ float waveReduceMin(float v){
  #pragma unroll
  for (int o=32;o>0;o>>=1) v = fminf(v, __shfl_down(v,o,64));
  return v;
}

// ---- register+shuffle 16x16 diagonal Cholesky (wave0 only) ----
// lane r (<16) holds row r. Fully unrolled: all reg indices static.
// On exit the DIAGONAL holds 1/l_kk (linv), off-diag holds L.
__device__ __forceinline__ void chol_diag_reg(float* tri, int c0, int lane){
  float row[16];
  const int r = lane;
  if (r < 16){
    const float* src = &tri[ROFF(c0+r)+c0];
    #pragma unroll
    for (int j=0;j<16;++j) row[j] = (j<=r)? src[j] : 0.f;
  } else {
    #pragma unroll
    for (int j=0;j<16;++j) row[j]=0.f;
  }
  #pragma unroll
  for (int k=0;k<16;++k){
    float akk = __shfl(row[k], k, 64);
    akk = fmaxf(akk, 1e-12f);
    float linv = rsqrtf(akk);
    linv = linv*(1.5f - 0.5f*akk*linv*linv);   // one Newton step -> ~1 ulp
    if (r == k)                 row[k] = linv;
    else if (r > k && r < 16)   row[k] *= linv;    // l_rk
    float lrk = row[k];
    #pragma unroll
    for (int j=k+1;j<16;++j){
      float ljk = __shfl(row[k], j, 64);           // lane j's scaled col-k entry
      if (r >= j && r < 16) row[j] = fmaf(-lrk, ljk, row[j]);
    }
  }
  if (r < 16){
    float* dst = &tri[ROFF(c0+r)+c0];
    #pragma unroll
    for (int j=0;j<=r;++j) dst[j] = row[j];
  }
}

// ---- blocked Cholesky on packed lower triangle (n=128, BS=16) ----
__device__ void chol_factor(float* tri, int t, int lane, int wid){
  for (int kb=0; kb<8; ++kb){
    const int c0 = kb*16;
    if (wid==0) chol_diag_reg(tri, c0, lane);
    __syncthreads();
    const int rem = 112 - c0;
    if (t < rem){                           // panel solve: row r vs diag block
      const int r = c0+16+t;
      const int rb = ROFF(r)+c0;
      float x[16], dg[16];
      #pragma unroll
      for (int c=0;c<16;++c) dg[c] = tri[ROFF(c0+c)+c0+c];   // linv (broadcast)
      #pragma unroll
      for (int c=0;c<16;++c){
        float v = tri[rb+c];
        #pragma unroll
        for (int cc=0;cc<c;++cc) v = fmaf(-x[cc], tri[ROFF(c0+c)+c0+cc], v);
        x[c] = v * dg[c];
      }
      #pragma unroll
      for (int c=0;c<16;++c) tri[rb+c] = x[c];
    }
    __syncthreads();
    if (rem > 0){                           // trailing update, 4x4 tiles
      const int base = c0+16;
      const int R = rem>>2;
      const int ntile = (R*(R+1))>>1;
      for (int idx=t; idx<ntile; idx+=256){
        int I = (int)((sqrtf(8.f*(float)idx+1.f)-1.f)*0.5f);
        while (((I+1)*(I+2)>>1) <= idx) ++I;
        while (((I*(I+1))>>1) > idx) --I;
        int J = idx - ((I*(I+1))>>1);
        int i0 = base + 4*I, j0 = base + 4*J;
        float Pi[4][16];
        #pragma unroll
        for (int ii=0;ii<4;++ii){
          int rb2 = ROFF(i0+ii)+c0;
          #pragma unroll
          for (int c=0;c<16;++c) Pi[ii][c] = tri[rb2+c];
        }
        float acc[4][4];
        #pragma unroll
        for (int jj=0;jj<4;++jj){
          int rbj = ROFF(j0+jj)+c0;
          float Pj[16];
          #pragma unroll
          for (int c=0;c<16;++c) Pj[c] = tri[rbj+c];
          #pragma unroll
          for (int ii=0;ii<4;++ii){
            float a0=0.f,a1=0.f,a2=0.f,a3=0.f;
            #pragma unroll
            for (int c=0;c<16;c+=4){
              a0 = fmaf(Pi[ii][c+0],Pj[c+0],a0);
              a1 = fmaf(Pi[ii][c+1],Pj[c+1],a1);
              a2 = fmaf(Pi[ii][c+2],Pj[c+2],a2);
              a3 = fmaf(Pi[ii][c+3],Pj[c+3],a3);
            }
            acc[ii][jj] = (a0+a1)+(a2+a3);
          }
        }
        #pragma unroll
        for (int ii=0;ii<4;++ii){
          #pragma unroll
          for (int jj=0;jj<4;++jj){
            int gi=i0+ii, gj=j0+jj;
            if (gi>=gj) tri[ROFF(gi)+gj] -= acc[ii][jj];
          }
        }
      }
    }
    __syncthreads();
  }
}

// forward (L y = rhs) then backward (L^T x = y), blocked BS=16, in place.
// Diagonal of tri holds linv -> multiplies. All chain operands prefetched.
__device__ void tri_solve_fb(const float* tri, float* rhs, int t, int lane, int wid){
  for (int kb=0;kb<8;++kb){
    const int c0=kb*16;
    if (wid==0){
      const int c = lane & 15;
      float dg[16], rowv[16];
      #pragma unroll
      for (int cp=0;cp<16;++cp) dg[cp] = tri[ROFF(c0+cp)+c0+cp];
      #pragma unroll
      for (int cp=0;cp<16;++cp) rowv[cp] = tri[ROFF(c0+c)+c0+cp];
      float v = rhs[c0+c];
      #pragma unroll
      for (int cp=0;cp<16;++cp){
        float yv = __shfl(v, cp, 64) * dg[cp];
        if (c>cp)       v = fmaf(-rowv[cp], yv, v);
        else if (c==cp) v = yv;
      }
      if (lane<16) rhs[c0+lane] = v;
    }
    __syncthreads();
    const int rem = 112-c0;
    if (t<rem){
      const int r = c0+16+t;
      const int rb = ROFF(r)+c0;
      float acc = rhs[r];
      #pragma unroll
      for (int c=0;c<16;++c) acc = fmaf(-tri[rb+c], rhs[c0+c], acc);
      rhs[r] = acc;
    }
    __syncthreads();
  }
  for (int kb=7;kb>=0;--kb){
    const int c0=kb*16;
    if (wid==0){
      const int c = lane & 15;
      float dg[16], colv[16];
      #pragma unroll
      for (int cp=0;cp<16;++cp) dg[cp] = tri[ROFF(c0+cp)+c0+cp];
      #pragma unroll
      for (int cp=0;cp<16;++cp) colv[cp] = (cp>c)? tri[ROFF(c0+cp)+c0+c] : 0.f;
      float v = rhs[c0+c];
      #pragma unroll
      for (int cp=15;cp>=0;--cp){
        float yv = __shfl(v, cp, 64)*dg[cp];
        if (c<cp)       v = fmaf(-colv[cp], yv, v);
        else if (c==cp) v = yv;
      }
      if (lane<16) rhs[c0+lane]=v;
    }
    __syncthreads();
    if (t<c0){
      float acc = rhs[t];
      #pragma unroll
      for (int c=0;c<16;++c) acc = fmaf(-tri[ROFF(c0+c)+t], rhs[c0+c], acc);
      rhs[t]=acc;
    }
    __syncthreads();
  }
}

// y[r] = sum_j mat[j*128+r] * x[j]
// MODE 0: out=sum ; MODE 1: out = -(e1+e2)+sum ; MODE 2: out = e1 - sum
template<int MODE>
__device__ __forceinline__ void matvecB(const float* __restrict__ mat,
                                        const float* __restrict__ xin,
                                        float* __restrict__ out,
                                        const float* __restrict__ e1,
                                        const float* __restrict__ e2,
                                        float* part, int t){
  const int r = t & 127;
  const int hf = t >> 7;
  const float* mp = mat + (hf<<6)*128 + r;
  const float* xp = xin + (hf<<6);
  float a0=0.f,a1=0.f,a2=0.f,a3=0.f;
  #pragma unroll
  for (int j=0;j<64;j+=4){
    a0 = fmaf(mp[(j+0)*128], xp[j+0], a0);
    a1 = fmaf(mp[(j+1)*128], xp[j+1], a1);
    a2 = fmaf(mp[(j+2)*128], xp[j+2], a2);
    a3 = fmaf(mp[(j+3)*128], xp[j+3], a3);
  }
  part[t] = (a0+a1)+(a2+a3);
  __syncthreads();
  if (t<128){
    float ssum = part[r] + part[r+128];
    if (MODE==0)      out[r] = ssum;
    else if (MODE==1) out[r] = -(e1[r]+e2[r]) + ssum;
    else              out[r] = e1[r] - ssum;
  }
  __syncthreads();
}

// rowOf LUT in global (shared by all k_ipm blocks, L2-resident)
__global__ __launch_bounds__(256) void k_rowof(unsigned char* __restrict__ rowOf){
  int idx = blockIdx.x*256 + threadIdx.x;
  if (idx < 8256){
    int i = (int)((sqrtf(8.f*(float)idx+1.f)-1.f)*0.5f);
    while (((i+1)*(i+2)>>1) <= idx) ++i;
    while (((i*(i+1))>>1) > idx) --i;
    rowOf[idx] = (unsigned char)i;
  }
}

// ---- precompute: chol(Q), then Qi = Q^{-1} and M1 = Qi G^T ----
__global__ __launch_bounds__(256) void k_prep(const float* __restrict__ Q,
        const float* __restrict__ Gm, float* __restrict__ Qi, float* __restrict__ M1)
{
  __shared__ float tri[8256];
  __shared__ unsigned char rowOf[8256];
  __shared__ float Xl[128*32];
  const int t = threadIdx.x;
  const int lane = t&63, wid = t>>6;
  for (int idx=t; idx<8256; idx+=256){
    int i = (int)((sqrtf(8.f*(float)idx+1.f)-1.f)*0.5f);
    while (((i+1)*(i+2)>>1) <= idx) ++i;
    while (((i*(i+1))>>1) > idx) --i;
    rowOf[idx] = (unsigned char)i;
  }
  __syncthreads();
  for (int idx=t; idx<8256; idx+=256){
    int i = rowOf[idx]; int j = idx - ((i*(i+1))>>1);
    tri[idx] = Q[i*128+j];
  }
  __syncthreads();
  chol_factor(tri, t, lane, wid);
  for (int cc=0; cc<8; ++cc){
    const int a0 = (cc&3)*32;
    const bool ident = (cc<4);
    for (int idx=t; idx<4096; idx+=256){
      int i=idx>>5, j=idx&31;
      Xl[idx] = ident ? ((i==(a0+j))?1.f:0.f) : Gm[(a0+j)*128+i];
    }
    __syncthreads();
    for (int kb=0;kb<8;++kb){                    // forward
      const int c0=kb*16;
      if (t<32){
        float x[16];
        #pragma unroll
        for (int c=0;c<16;++c){
          float v = Xl[(c0+c)*32+t];
          #pragma unroll
          for (int cp=0;cp<c;++cp) v = fmaf(-tri[ROFF(c0+c)+c0+cp], x[cp], v);
          x[c] = v*tri[ROFF(c0+c)+c0+c];         // * linv
        }
        #pragma unroll
        for (int c=0;c<16;++c) Xl[(c0+c)*32+t] = x[c];
      }
      __syncthreads();
      const int rem=112-c0;
      for (int rr=(t>>5); rr<rem; rr+=8){
        const int r=c0+16+rr, j=t&31;
        float acc=Xl[r*32+j];
        #pragma unroll
        for (int c=0;c<16;++c) acc = fmaf(-tri[ROFF(r)+c0+c], Xl[(c0+c)*32+j], acc);
        Xl[r*32+j]=acc;
      }
      __syncthreads();
    }
    for (int kb=7;kb>=0;--kb){                   // backward
      const int c0=kb*16;
      if (t<32){
        float x[16];
        #pragma unroll
        for (int c=15;c>=0;--c){
          float v = Xl[(c0+c)*32+t];
          #pragma unroll
          for (int cp=c+1;cp<16;++cp) v = fmaf(-tri[ROFF(c0+cp)+c0+c], x[cp], v);
          x[c] = v*tri[ROFF(c0+c)+c0+c];         // * linv
        }
        #pragma unroll
        for (int c=0;c<16;++c) Xl[(c0+c)*32+t]=x[c];
      }
      __syncthreads();
      for (int rr=(t>>5); rr<c0; rr+=8){
        const int j=t&31;
        float acc=Xl[rr*32+j];
        #pragma unroll
        for (int c=0;c<16;++c) acc = fmaf(-tri[ROFF(c0+c)+rr], Xl[(c0+c)*32+j], acc);
        Xl[rr*32+j]=acc;
      }
      __syncthreads();
    }
    float* dst = ident ? Qi : M1;
    for (int idx=t; idx<4096; idx+=256){
      int i=idx>>5, j=idx&31;
      dst[i*128+a0+j] = Xl[idx];
    }
    __syncthreads();
  }
}

// K = G * M1  (= G Qi G^T), plus its diagonal
__global__ __launch_bounds__(256) void k_kmat(const float* __restrict__ Gm,
        const float* __restrict__ M1, float* __restrict__ K, float* __restrict__ Kd){
  const int idx = blockIdx.x*256 + threadIdx.x;
  const int a = idx>>7, bcol = idx&127;
  float a0=0.f,a1=0.f,a2=0.f,a3=0.f;
  #pragma unroll
  for (int j=0;j<128;j+=4){
    a0 = fmaf(Gm[a*128+j+0], M1[(j+0)*128+bcol], a0);
    a1 = fmaf(Gm[a*128+j+1], M1[(j+1)*128+bcol], a1);
    a2 = fmaf(Gm[a*128+j+2], M1[(j+2)*128+bcol], a2);
    a3 = fmaf(Gm[a*128+j+3], M1[(j+3)*128+bcol], a3);
  }
  float acc = (a0+a1)+(a2+a3);
  K[idx] = acc;
  if (a==bcol) Kd[a]=acc;
}

// ---- main: one block per batch, 20 IPM iterations ----
__global__ __launch_bounds__(256,3) void k_ipm(const float* __restrict__ Q,
      const float* __restrict__ G, const float* __restrict__ p,
      const float* __restrict__ h, const float* __restrict__ Qi,
      const float* __restrict__ M1, const float* __restrict__ K,
      const float* __restrict__ Kd, const unsigned char* __restrict__ rowOf_g,
      float* __restrict__ Z)
{
  __shared__ float tri[8256];
  __shared__ float sh_z[128], sh_s[128], sh_lam[128], sh_gz[128], sh_qz[128];
  __shared__ float sh_wm[128];
  __shared__ float sh_rhs[128], sh_t[128], sh_v[128], sh_dz[128];
  __shared__ float sh_p[128], sh_h[128], sh_Kd[128], sh_scl[128];
  __shared__ float part[256];
  __shared__ float red[4];
  const int t = threadIdx.x, b = blockIdx.x;
  const int lane = t & 63, wid = t >> 6;

  if (t<128){
    sh_z[t]=0.f; sh_gz[t]=0.f; sh_s[t]=1.f; sh_lam[t]=1.f;
    sh_p[t]=p[b*128+t]; sh_h[t]=h[t]; sh_Kd[t]=Kd[t];
  }
  __syncthreads();

  for (int it=0; it<20; ++it){
    // qz = Q z
    matvecB<0>(Q, sh_z, sh_qz, nullptr, nullptr, part, t);
    float s_t=0.f, lam_t=0.f, rp_t=0.f, prod=0.f;
    if (t<128){
      s_t = sh_s[t]; lam_t = sh_lam[t];
      rp_t = sh_gz[t] + s_t - sh_h[t];       // r_p = Gz + s - h (Gz maintained)
      prod = s_t*lam_t;
    }
    prod = waveReduceSum(prod);
    if (lane==0) red[wid]=prod;
    __syncthreads();
    const float mu = (red[0]+red[1]+red[2]+red[3]) * (1.f/128.f);
    float rc_t=0.f, dinv_t=0.f;
    if (t<128){
      rc_t = s_t*lam_t - 0.1f*mu;            // r_c = s.lam - sigma*mu
      dinv_t = fminf(s_t/lam_t, 1e30f);      // D^{-1}, overflow-guarded
      float w = (rc_t - lam_t*rp_t)/s_t;
      sh_wm[t] = w - lam_t;
      sh_scl[t] = rsqrtf(sh_Kd[t] + dinv_t); // equilibration scale
    }
    __syncthreads();
    // rhs = -(qz+p) + G^T (w - lam)
    matvecB<1>(G, sh_wm, sh_rhs, sh_qz, sh_p, part, t);
    // tvec = G Qi rhs  (via M1 = Qi G^T)
    matvecB<0>(M1, sh_rhs, sh_t, nullptr, nullptr, part, t);
    // equilibrated A' = S(Dinv+K)S (unit diag), scale rhs
    if (t<128) sh_t[t] *= sh_scl[t];
    for (int idx=t; idx<8256; idx+=256){
      int i = rowOf_g[idx];
      int j = idx - ((i*(i+1))>>1);
      float v = (i==j) ? 1.0f : K[i*128+j]*sh_scl[i]*sh_scl[j];
      tri[idx]=v;
    }
    __syncthreads();
    chol_factor(tri, t, lane, wid);
    tri_solve_fb(tri, sh_t, t, lane, wid);
    if (t<128) sh_t[t] *= sh_scl[t];         // y = S y'
    __syncthreads();
    float gdz_t=0.f, ds_t=0.f, dlam_t=0.f;
    if (t<128){
      float y = sh_t[t];
      gdz_t = dinv_t*y;                      // G dz = Dinv .* y (Woodbury identity)
      ds_t = -rp_t - gdz_t;
      dlam_t = (-rc_t - lam_t*ds_t)/s_t;
    }
    // v = rhs - G^T y ;  dz = Qi v
    matvecB<2>(G, sh_t, sh_v, sh_rhs, nullptr, part, t);
    matvecB<0>(Qi, sh_v, sh_dz, nullptr, nullptr, part, t);
    // fraction-to-boundary step
    float ra = 1e9f;
    if (t<128){
      if (ds_t   < 0.f) ra = -s_t/ds_t;
      if (dlam_t < 0.f) ra = fminf(ra, -lam_t/dlam_t);
    }
    ra = waveReduceMin(ra);
    if (lane==0) red[wid]=ra;
    __syncthreads();
    const float rmin = fminf(fminf(red[0],red[1]), fminf(red[2],red[3]));
    const float alpha = fminf(1.0f, 0.99f*rmin);
    if (t<128){
      sh_z[t]  += alpha*sh_dz[t];
      sh_s[t]   = s_t + alpha*ds_t;
      sh_lam[t] = lam_t + alpha*dlam_t;
      sh_gz[t] += alpha*gdz_t;               // Gz incremental
    }
    __syncthreads();
  }
  if (t<128) Z[b*128+t] = sh_z[t];
}

// out = log_softmax(Z.reshape(10, 32768), axis=1)
__global__ __launch_bounds__(1024) void k_logsoftmax(const float* __restrict__ Z,
                                                     float* __restrict__ out){
  __shared__ float red[16];
  __shared__ float sval[2];
  const int r = blockIdx.x, t = threadIdx.x;
  const float* zp = Z + (size_t)r*32768;
  float m = -1e30f;
  for (int i=t;i<32768;i+=1024) m = fmaxf(m, zp[i]);
  #pragma unroll
  for (int o=32;o>0;o>>=1) m = fmaxf(m, __shfl_down(m,o,64));
  if ((t&63)==0) red[t>>6] = m;
  __syncthreads();
  if (t==0){ float mm=red[0]; for (int w=1;w<16;++w) mm=fmaxf(mm,red[w]); sval[0]=mm; }
  __syncthreads();
  const float mx = sval[0];
  float s=0.f;
  for (int i=t;i<32768;i+=1024) s += expf(zp[i]-mx);
  #pragma unroll
  for (int o=32;o>0;o>>=1) s += __shfl_down(s,o,64);
  if ((t&63)==0) red[t>>6]=s;
  __syncthreads();
  if (t==0){ float ss=0.f; for (int w=0;w<16;++w) ss+=red[w]; sval[1]=logf(ss); }
  __syncthreads();
  const float lse = sval[1];
  for (int i=t;i<32768;i+=1024) out[(size_t)r*32768+i] = zp[i]-mx-lse;
}

extern "C" void kernel_launch(void* const* d_in, const int* in_sizes, int n_in,
                              void* d_out, int out_size, void* d_ws, size_t ws_size,
                              hipStream_t stream){
  // inputs: 0=x (unused), 1=Q[128x128], 2=p[2560x128], 3=G[128x128], 4=h[128], 5=m
  const float* Q = (const float*)d_in[1];
  const float* p = (const float*)d_in[2];
  const float* G = (const float*)d_in[3];
  const float* h = (const float*)d_in[4];
  float* ws = (float*)d_ws;
  float* Z  = ws;                 // 327680
  float* Qi = Z + 327680;         // 16384
  float* M1 = Qi + 16384;         // 16384
  float* K  = M1 + 16384;         // 16384
  float* Kd = K + 16384;          // 128
  unsigned char* rowOf_g = (unsigned char*)(Kd + 128);  // 8256 bytes
  float* out = (float*)d_out;

  hipLaunchKernelGGL(k_rowof, dim3(33), dim3(256), 0, stream, rowOf_g);
  hipLaunchKernelGGL(k_prep, dim3(1), dim3(256), 0, stream, Q, G, Qi, M1);
  hipLaunchKernelGGL(k_kmat, dim3(64), dim3(256), 0, stream, G, M1, K, Kd);
  hipLaunchKernelGGL(k_ipm,  dim3(2560), dim3(256), 0, stream,
                     Q, G, p, h, Qi, M1, K, Kd, rowOf_g, Z);
  hipLaunchKernelGGL(k_logsoftmax, dim3(10), dim3(1024), 0, stream, Z, out);
}

// Round 3
// 23438.310 us; speedup vs baseline: 1.4259x; 1.4259x over previous
//
#include <hip/hip_runtime.h>
#include <math.h>

// OptNet IPM QP solve via Woodbury:
//  M = Q + G^T D G;  M^{-1} = Qi - Qi G^T (Dinv + K)^{-1} G Qi,  K = G Qi G^T
// Round 3: spill elimination. Round-2 counters showed WRITE_SIZE=1.17GB vs 1.25MB
// of program writes => register-spill scratch thrashing per-XCD L2 and evicting
// the shared matrices (FETCH=10.7GB on a 320KB hot set). Changes:
//  - __launch_bounds__(256) (no min-wave cap) so the compiler never spills
//  - qz maintained incrementally (qz += alpha*v, since Q dz == v): Q matvec dropped
//  - rowOf LUT computed arithmetically (no recurring global LUT stream)

__device__ __forceinline__ int ROFF(int i){ return (i*(i+1))>>1; }

__device__ __forceinline__ float waveReduceSum(float v){
  #pragma unroll
  for (int o=32;o>0;o>>=1) v += __shfl_down(v,o,64);
  return v;
}
__device__ __forceinline__ float waveReduceMin(float v){
  #pragma unroll
  for (int o=32;o>0;o>>=1) v = fminf(v, __shfl_down(v,o,64));
  return v;
}

__device__ __forceinline__ int rowOfIdx(int idx){
  int i = (int)((sqrtf(8.f*(float)idx+1.f)-1.f)*0.5f);
  while (((i+1)*(i+2)>>1) <= idx) ++i;
  while (((i*(i+1))>>1) > idx) --i;
  return i;
}

// ---- register+shuffle 16x16 diagonal Cholesky (wave0 only) ----
// lane r (<16) holds row r. On exit the DIAGONAL holds 1/l_kk, off-diag holds L.
__device__ __forceinline__ void chol_diag_reg(float* tri, int c0, int lane){
  float row[16];
  const int r = lane;
  if (r < 16){
    const float* src = &tri[ROFF(c0+r)+c0];
    #pragma unroll
    for (int j=0;j<16;++j) row[j] = (j<=r)? src[j] : 0.f;
  } else {
    #pragma unroll
    for (int j=0;j<16;++j) row[j]=0.f;
  }
  #pragma unroll
  for (int k=0;k<16;++k){
    float akk = __shfl(row[k], k, 64);
    akk = fmaxf(akk, 1e-12f);
    float linv = rsqrtf(akk);
    linv = linv*(1.5f - 0.5f*akk*linv*linv);   // one Newton step
    if (r == k)                 row[k] = linv;
    else if (r > k && r < 16)   row[k] *= linv;    // l_rk
    float lrk = row[k];
    #pragma unroll
    for (int j=k+1;j<16;++j){
      float ljk = __shfl(row[k], j, 64);
      if (r >= j && r < 16) row[j] = fmaf(-lrk, ljk, row[j]);
    }
  }
  if (r < 16){
    float* dst = &tri[ROFF(c0+r)+c0];
    #pragma unroll
    for (int j=0;j<=r;++j) dst[j] = row[j];
  }
}

// ---- blocked Cholesky on packed lower triangle (n=128, BS=16) ----
__device__ void chol_factor(float* tri, int t, int lane, int wid){
  for (int kb=0; kb<8; ++kb){
    const int c0 = kb*16;
    if (wid==0) chol_diag_reg(tri, c0, lane);
    __syncthreads();
    const int rem = 112 - c0;
    if (t < rem){                           // panel solve: row r vs diag block
      const int r = c0+16+t;
      const int rb = ROFF(r)+c0;
      float x[16], dg[16];
      #pragma unroll
      for (int c=0;c<16;++c) dg[c] = tri[ROFF(c0+c)+c0+c];   // linv
      #pragma unroll
      for (int c=0;c<16;++c){
        float v = tri[rb+c];
        #pragma unroll
        for (int cc=0;cc<c;++cc) v = fmaf(-x[cc], tri[ROFF(c0+c)+c0+cc], v);
        x[c] = v * dg[c];
      }
      #pragma unroll
      for (int c=0;c<16;++c) tri[rb+c] = x[c];
    }
    __syncthreads();
    if (rem > 0){                           // trailing update, 4x4 tiles
      const int base = c0+16;
      const int R = rem>>2;
      const int ntile = (R*(R+1))>>1;
      for (int idx=t; idx<ntile; idx+=256){
        int I = rowOfIdx(idx);
        int J = idx - ((I*(I+1))>>1);
        int i0 = base + 4*I, j0 = base + 4*J;
        float Pi[4][16];
        #pragma unroll
        for (int ii=0;ii<4;++ii){
          int rb2 = ROFF(i0+ii)+c0;
          #pragma unroll
          for (int c=0;c<16;++c) Pi[ii][c] = tri[rb2+c];
        }
        float acc[4][4];
        #pragma unroll
        for (int jj=0;jj<4;++jj){
          int rbj = ROFF(j0+jj)+c0;
          float Pj[16];
          #pragma unroll
          for (int c=0;c<16;++c) Pj[c] = tri[rbj+c];
          #pragma unroll
          for (int ii=0;ii<4;++ii){
            float a0=0.f,a1=0.f,a2=0.f,a3=0.f;
            #pragma unroll
            for (int c=0;c<16;c+=4){
              a0 = fmaf(Pi[ii][c+0],Pj[c+0],a0);
              a1 = fmaf(Pi[ii][c+1],Pj[c+1],a1);
              a2 = fmaf(Pi[ii][c+2],Pj[c+2],a2);
              a3 = fmaf(Pi[ii][c+3],Pj[c+3],a3);
            }
            acc[ii][jj] = (a0+a1)+(a2+a3);
          }
        }
        #pragma unroll
        for (int ii=0;ii<4;++ii){
          #pragma unroll
          for (int jj=0;jj<4;++jj){
            int gi=i0+ii, gj=j0+jj;
            if (gi>=gj) tri[ROFF(gi)+gj] -= acc[ii][jj];
          }
        }
      }
    }
    __syncthreads();
  }
}

// forward (L y = rhs) then backward (L^T x = y), blocked BS=16, in place.
__device__ void tri_solve_fb(const float* tri, float* rhs, int t, int lane, int wid){
  for (int kb=0;kb<8;++kb){
    const int c0=kb*16;
    if (wid==0){
      const int c = lane & 15;
      float dg[16], rowv[16];
      #pragma unroll
      for (int cp=0;cp<16;++cp) dg[cp] = tri[ROFF(c0+cp)+c0+cp];
      #pragma unroll
      for (int cp=0;cp<16;++cp) rowv[cp] = tri[ROFF(c0+c)+c0+cp];
      float v = rhs[c0+c];
      #pragma unroll
      for (int cp=0;cp<16;++cp){
        float yv = __shfl(v, cp, 64) * dg[cp];
        if (c>cp)       v = fmaf(-rowv[cp], yv, v);
        else if (c==cp) v = yv;
      }
      if (lane<16) rhs[c0+lane] = v;
    }
    __syncthreads();
    const int rem = 112-c0;
    if (t<rem){
      const int r = c0+16+t;
      const int rb = ROFF(r)+c0;
      float acc = rhs[r];
      #pragma unroll
      for (int c=0;c<16;++c) acc = fmaf(-tri[rb+c], rhs[c0+c], acc);
      rhs[r] = acc;
    }
    __syncthreads();
  }
  for (int kb=7;kb>=0;--kb){
    const int c0=kb*16;
    if (wid==0){
      const int c = lane & 15;
      float dg[16], colv[16];
      #pragma unroll
      for (int cp=0;cp<16;++cp) dg[cp] = tri[ROFF(c0+cp)+c0+cp];
      #pragma unroll
      for (int cp=0;cp<16;++cp) colv[cp] = (cp>c)? tri[ROFF(c0+cp)+c0+c] : 0.f;
      float v = rhs[c0+c];
      #pragma unroll
      for (int cp=15;cp>=0;--cp){
        float yv = __shfl(v, cp, 64)*dg[cp];
        if (c<cp)       v = fmaf(-colv[cp], yv, v);
        else if (c==cp) v = yv;
      }
      if (lane<16) rhs[c0+lane]=v;
    }
    __syncthreads();
    if (t<c0){
      float acc = rhs[t];
      #pragma unroll
      for (int c=0;c<16;++c) acc = fmaf(-tri[ROFF(c0+c)+t], rhs[c0+c], acc);
      rhs[t]=acc;
    }
    __syncthreads();
  }
}

// y[r] = sum_j mat[j*128+r] * x[j]
// MODE 0: out=sum ; MODE 1: out = -(e1+e2)+sum ; MODE 2: out = e1 - sum
template<int MODE>
__device__ __forceinline__ void matvecB(const float* __restrict__ mat,
                                        const float* __restrict__ xin,
                                        float* __restrict__ out,
                                        const float* __restrict__ e1,
                                        const float* __restrict__ e2,
                                        float* part, int t){
  const int r = t & 127;
  const int hf = t >> 7;
  const float* mp = mat + (hf<<6)*128 + r;
  const float* xp = xin + (hf<<6);
  float a0=0.f,a1=0.f,a2=0.f,a3=0.f;
  #pragma unroll
  for (int j=0;j<64;j+=4){
    a0 = fmaf(mp[(j+0)*128], xp[j+0], a0);
    a1 = fmaf(mp[(j+1)*128], xp[j+1], a1);
    a2 = fmaf(mp[(j+2)*128], xp[j+2], a2);
    a3 = fmaf(mp[(j+3)*128], xp[j+3], a3);
  }
  part[t] = (a0+a1)+(a2+a3);
  __syncthreads();
  if (t<128){
    float ssum = part[r] + part[r+128];
    if (MODE==0)      out[r] = ssum;
    else if (MODE==1) out[r] = -(e1[r]+e2[r]) + ssum;
    else              out[r] = e1[r] - ssum;
  }
  __syncthreads();
}

// ---- precompute: chol(Q), then Qi = Q^{-1} and M1 = Qi G^T ----
__global__ __launch_bounds__(256) void k_prep(const float* __restrict__ Q,
        const float* __restrict__ Gm, float* __restrict__ Qi, float* __restrict__ M1)
{
  __shared__ float tri[8256];
  __shared__ float Xl[128*32];
  const int t = threadIdx.x;
  const int lane = t&63, wid = t>>6;
  for (int idx=t; idx<8256; idx+=256){
    int i = rowOfIdx(idx); int j = idx - ((i*(i+1))>>1);
    tri[idx] = Q[i*128+j];
  }
  __syncthreads();
  chol_factor(tri, t, lane, wid);
  for (int cc=0; cc<8; ++cc){
    const int a0 = (cc&3)*32;
    const bool ident = (cc<4);
    for (int idx=t; idx<4096; idx+=256){
      int i=idx>>5, j=idx&31;
      Xl[idx] = ident ? ((i==(a0+j))?1.f:0.f) : Gm[(a0+j)*128+i];
    }
    __syncthreads();
    for (int kb=0;kb<8;++kb){                    // forward
      const int c0=kb*16;
      if (t<32){
        float x[16];
        #pragma unroll
        for (int c=0;c<16;++c){
          float v = Xl[(c0+c)*32+t];
          #pragma unroll
          for (int cp=0;cp<c;++cp) v = fmaf(-tri[ROFF(c0+c)+c0+cp], x[cp], v);
          x[c] = v*tri[ROFF(c0+c)+c0+c];         // * linv
        }
        #pragma unroll
        for (int c=0;c<16;++c) Xl[(c0+c)*32+t] = x[c];
      }
      __syncthreads();
      const int rem=112-c0;
      for (int rr=(t>>5); rr<rem; rr+=8){
        const int r=c0+16+rr, j=t&31;
        float acc=Xl[r*32+j];
        #pragma unroll
        for (int c=0;c<16;++c) acc = fmaf(-tri[ROFF(r)+c0+c], Xl[(c0+c)*32+j], acc);
        Xl[r*32+j]=acc;
      }
      __syncthreads();
    }
    for (int kb=7;kb>=0;--kb){                   // backward
      const int c0=kb*16;
      if (t<32){
        float x[16];
        #pragma unroll
        for (int c=15;c>=0;--c){
          float v = Xl[(c0+c)*32+t];
          #pragma unroll
          for (int cp=c+1;cp<16;++cp) v = fmaf(-tri[ROFF(c0+cp)+c0+c], x[cp], v);
          x[c] = v*tri[ROFF(c0+c)+c0+c];         // * linv
        }
        #pragma unroll
        for (int c=0;c<16;++c) Xl[(c0+c)*32+t]=x[c];
      }
      __syncthreads();
      for (int rr=(t>>5); rr<c0; rr+=8){
        const int j=t&31;
        float acc=Xl[rr*32+j];
        #pragma unroll
        for (int c=0;c<16;++c) acc = fmaf(-tri[ROFF(c0+c)+rr], Xl[(c0+c)*32+j], acc);
        Xl[rr*32+j]=acc;
      }
      __syncthreads();
    }
    float* dst = ident ? Qi : M1;
    for (int idx=t; idx<4096; idx+=256){
      int i=idx>>5, j=idx&31;
      dst[i*128+a0+j] = Xl[idx];
    }
    __syncthreads();
  }
}

// K = G * M1  (= G Qi G^T), plus its diagonal
__global__ __launch_bounds__(256) void k_kmat(const float* __restrict__ Gm,
        const float* __restrict__ M1, float* __restrict__ K, float* __restrict__ Kd){
  const int idx = blockIdx.x*256 + threadIdx.x;
  const int a = idx>>7, bcol = idx&127;
  float a0=0.f,a1=0.f,a2=0.f,a3=0.f;
  #pragma unroll
  for (int j=0;j<128;j+=4){
    a0 = fmaf(Gm[a*128+j+0], M1[(j+0)*128+bcol], a0);
    a1 = fmaf(Gm[a*128+j+1], M1[(j+1)*128+bcol], a1);
    a2 = fmaf(Gm[a*128+j+2], M1[(j+2)*128+bcol], a2);
    a3 = fmaf(Gm[a*128+j+3], M1[(j+3)*128+bcol], a3);
  }
  float acc = (a0+a1)+(a2+a3);
  K[idx] = acc;
  if (a==bcol) Kd[a]=acc;
}

// ---- main: one block per batch, 20 IPM iterations ----
__global__ __launch_bounds__(256) void k_ipm(
      const float* __restrict__ G, const float* __restrict__ p,
      const float* __restrict__ h, const float* __restrict__ Qi,
      const float* __restrict__ M1, const float* __restrict__ K,
      const float* __restrict__ Kd, float* __restrict__ Z)
{
  __shared__ float tri[8256];
  __shared__ float sh_z[128], sh_s[128], sh_lam[128], sh_gz[128], sh_qz[128];
  __shared__ float sh_wm[128];
  __shared__ float sh_rhs[128], sh_t[128], sh_v[128], sh_dz[128];
  __shared__ float sh_p[128], sh_h[128], sh_Kd[128], sh_scl[128];
  __shared__ float part[256];
  __shared__ float red[4];
  const int t = threadIdx.x, b = blockIdx.x;
  const int lane = t & 63, wid = t >> 6;

  if (t<128){
    sh_z[t]=0.f; sh_gz[t]=0.f; sh_qz[t]=0.f; sh_s[t]=1.f; sh_lam[t]=1.f;
    sh_p[t]=p[b*128+t]; sh_h[t]=h[t]; sh_Kd[t]=Kd[t];
  }
  __syncthreads();

  for (int it=0; it<20; ++it){
    float s_t=0.f, lam_t=0.f, rp_t=0.f, prod=0.f;
    if (t<128){
      s_t = sh_s[t]; lam_t = sh_lam[t];
      rp_t = sh_gz[t] + s_t - sh_h[t];       // r_p = Gz + s - h (Gz maintained)
      prod = s_t*lam_t;
    }
    prod = waveReduceSum(prod);
    if (lane==0) red[wid]=prod;
    __syncthreads();
    const float mu = (red[0]+red[1]+red[2]+red[3]) * (1.f/128.f);
    float rc_t=0.f, dinv_t=0.f;
    if (t<128){
      rc_t = s_t*lam_t - 0.1f*mu;            // r_c = s.lam - sigma*mu
      dinv_t = fminf(s_t/lam_t, 1e30f);      // D^{-1}, overflow-guarded
      float w = (rc_t - lam_t*rp_t)/s_t;
      sh_wm[t] = w - lam_t;
      sh_scl[t] = rsqrtf(sh_Kd[t] + dinv_t); // equilibration scale
    }
    __syncthreads();
    // rhs = -(qz+p) + G^T (w - lam)   (qz maintained incrementally)
    matvecB<1>(G, sh_wm, sh_rhs, sh_qz, sh_p, part, t);
    // tvec = G Qi rhs  (via M1 = Qi G^T)
    matvecB<0>(M1, sh_rhs, sh_t, nullptr, nullptr, part, t);
    // equilibrated A' = S(Dinv+K)S (unit diag), scale rhs
    if (t<128) sh_t[t] *= sh_scl[t];
    for (int idx=t; idx<8256; idx+=256){
      int i = rowOfIdx(idx);
      int j = idx - ((i*(i+1))>>1);
      float v = (i==j) ? 1.0f : K[i*128+j]*sh_scl[i]*sh_scl[j];
      tri[idx]=v;
    }
    __syncthreads();
    chol_factor(tri, t, lane, wid);
    tri_solve_fb(tri, sh_t, t, lane, wid);
    if (t<128) sh_t[t] *= sh_scl[t];         // y = S y'
    __syncthreads();
    float gdz_t=0.f, ds_t=0.f, dlam_t=0.f;
    if (t<128){
      float y = sh_t[t];
      gdz_t = dinv_t*y;                      // G dz = Dinv .* y (Woodbury identity)
      ds_t = -rp_t - gdz_t;
      dlam_t = (-rc_t - lam_t*ds_t)/s_t;
    }
    // v = rhs - G^T y ;  dz = Qi v ;  note Q dz == v (used for qz update)
    matvecB<2>(G, sh_t, sh_v, sh_rhs, nullptr, part, t);
    matvecB<0>(Qi, sh_v, sh_dz, nullptr, nullptr, part, t);
    // fraction-to-boundary step
    float ra = 1e9f;
    if (t<128){
      if (ds_t   < 0.f) ra = -s_t/ds_t;
      if (dlam_t < 0.f) ra = fminf(ra, -lam_t/dlam_t);
    }
    ra = waveReduceMin(ra);
    if (lane==0) red[wid]=ra;
    __syncthreads();
    const float rmin = fminf(fminf(red[0],red[1]), fminf(red[2],red[3]));
    const float alpha = fminf(1.0f, 0.99f*rmin);
    if (t<128){
      sh_z[t]  += alpha*sh_dz[t];
      sh_s[t]   = s_t + alpha*ds_t;
      sh_lam[t] = lam_t + alpha*dlam_t;
      sh_gz[t] += alpha*gdz_t;               // Gz incremental
      sh_qz[t] += alpha*sh_v[t];             // Qz incremental (Q dz == v)
    }
    __syncthreads();
  }
  if (t<128) Z[b*128+t] = sh_z[t];
}

// out = log_softmax(Z.reshape(10, 32768), axis=1)
__global__ __launch_bounds__(1024) void k_logsoftmax(const float* __restrict__ Z,
                                                     float* __restrict__ out){
  __shared__ float red[16];
  __shared__ float sval[2];
  const int r = blockIdx.x, t = threadIdx.x;
  const float* zp = Z + (size_t)r*32768;
  float m = -1e30f;
  for (int i=t;i<32768;i+=1024) m = fmaxf(m, zp[i]);
  #pragma unroll
  for (int o=32;o>0;o>>=1) m = fmaxf(m, __shfl_down(m,o,64));
  if ((t&63)==0) red[t>>6] = m;
  __syncthreads();
  if (t==0){ float mm=red[0]; for (int w=1;w<16;++w) mm=fmaxf(mm,red[w]); sval[0]=mm; }
  __syncthreads();
  const float mx = sval[0];
  float s=0.f;
  for (int i=t;i<32768;i+=1024) s += expf(zp[i]-mx);
  #pragma unroll
  for (int o=32;o>0;o>>=1) s += __shfl_down(s,o,64);
  if ((t&63)==0) red[t>>6]=s;
  __syncthreads();
  if (t==0){ float ss=0.f; for (int w=0;w<16;++w) ss+=red[w]; sval[1]=logf(ss); }
  __syncthreads();
  const float lse = sval[1];
  for (int i=t;i<32768;i+=1024) out[(size_t)r*32768+i] = zp[i]-mx-lse;
}

extern "C" void kernel_launch(void* const* d_in, const int* in_sizes, int n_in,
                              void* d_out, int out_size, void* d_ws, size_t ws_size,
                              hipStream_t stream){
  // inputs: 0=x (unused), 1=Q[128x128], 2=p[2560x128], 3=G[128x128], 4=h[128], 5=m
  const float* Q = (const float*)d_in[1];
  const float* p = (const float*)d_in[2];
  const float* G = (const float*)d_in[3];
  const float* h = (const float*)d_in[4];
  float* ws = (float*)d_ws;
  float* Z  = ws;                 // 327680
  float* Qi = Z + 327680;         // 16384
  float* M1 = Qi + 16384;         // 16384
  float* K  = M1 + 16384;         // 16384
  float* Kd = K + 16384;          // 128
  float* out = (float*)d_out;

  hipLaunchKernelGGL(k_prep, dim3(1), dim3(256), 0, stream, Q, G, Qi, M1);
  hipLaunchKernelGGL(k_kmat, dim3(64), dim3(256), 0, stream, G, M1, K, Kd);
  hipLaunchKernelGGL(k_ipm,  dim3(2560), dim3(256), 0, stream,
                     G, p, h, Qi, M1, K, Kd, Z);
  hipLaunchKernelGGL(k_logsoftmax, dim3(10), dim3(1024), 0, stream, Z, out);
}

// Round 4
// 19837.737 us; speedup vs baseline: 1.6847x; 1.1815x over previous
//
#include <hip/hip_runtime.h>
#include <math.h>

// OptNet IPM QP solve via Woodbury:
//  M = Q + G^T D G;  M^{-1} = Qi - Qi G^T (Dinv + K)^{-1} G Qi,  K = G Qi G^T
// Round 4: spill-proof Cholesky. Diagonal 16x16 blocks are factored by one wave
// (rotating across waves) via Gauss-Jordan that ALSO produces Linv = inv(L_diag),
// stored in the diag slots. All triangular recurrences (panel solve, tri-solve
// diag steps) become pure dot products against Linv -> no serial register
// recurrences -> nothing for the compiler to hoist/spill. Triangle stored with
// 16B-aligned padded rows so panels/trailing use ds_read_b128.

__device__ __forceinline__ int ROFF(int i){ return (i*(i+1))>>1; }

// padded-row packed lower triangle: row i starts at rowStart(i), 16B aligned
__device__ __forceinline__ int rowStart(int i){
  int a=i>>2, b=i&3;
  return ((a+1)*((a<<1)+b))<<2;
}
#define TRI_SZ 8448   // rowStart(127)+128

__device__ __forceinline__ float waveReduceSum(float v){
  #pragma unroll
  for (int o=32;o>0;o>>=1) v += __shfl_down(v,o,64);
  return v;
}
__device__ __forceinline__ float waveReduceMin(float v){
  #pragma unroll
  for (int o=32;o>0;o>>=1) v = fminf(v, __shfl_down(v,o,64));
  return v;
}

__device__ __forceinline__ int rowOfIdx(int idx){
  int i = (int)((sqrtf(8.f*(float)idx+1.f)-1.f)*0.5f);
  while (((i+1)*(i+2)>>1) <= idx) ++i;
  while (((i*(i+1))>>1) > idx) --i;
  return i;
}

// ---- Gauss-Jordan 16x16 diag block: factor AND invert (one wave) ----
// lane r (<16) holds row r of A (lower) and of W (-> Linv). On exit the diag
// block slots hold Linv (lower triangular), replacing L_diag.
__device__ __forceinline__ void chol_diag_gj(float* tri, int c0, int lane){
  float rowA[16], rowW[16];
  const int r = lane;
  #pragma unroll
  for (int j=0;j<16;++j){ rowA[j]=0.f; rowW[j]=0.f; }
  if (r < 16){
    const float* src = &tri[rowStart(c0+r)+c0];
    #pragma unroll
    for (int q=0;q<4;++q){
      if (q <= (r>>2)){
        float4 w = *(const float4*)&src[4*q];
        rowA[4*q+0]=w.x; rowA[4*q+1]=w.y; rowA[4*q+2]=w.z; rowA[4*q+3]=w.w;
      }
    }
    #pragma unroll
    for (int j=0;j<16;++j) if (j>r) rowA[j]=0.f;
    #pragma unroll
    for (int j=0;j<16;++j) rowW[j] = (j==r)?1.f:0.f;
  }
  #pragma unroll
  for (int k=0;k<16;++k){
    float akk = __shfl(rowA[k], k, 64);
    akk = fmaxf(akk, 1e-12f);
    float linv = rsqrtf(akk);
    linv = linv*(1.5f - 0.5f*akk*linv*linv);   // Newton step
    float lrk = rowA[k]*linv;                  // valid for r>=k
    if (r==k){
      #pragma unroll
      for (int c=0;c<16;++c) rowW[c] *= linv;  // final Linv row k
    }
    #pragma unroll
    for (int j=k+1;j<16;++j){
      float ljk = __shfl(lrk, j, 64);
      if (r>=j) rowA[j] = fmaf(-lrk, ljk, rowA[j]);
    }
    #pragma unroll
    for (int c=0;c<=k;++c){
      float wkc = __shfl(rowW[c], k, 64);      // already scaled (lane k done above)
      if (r>k) rowW[c] = fmaf(-lrk, wkc, rowW[c]);
    }
  }
  if (r < 16){
    float* dst = &tri[rowStart(c0+r)+c0];
    #pragma unroll
    for (int q=0;q<4;++q){
      if (q <= (r>>2)){
        float4 w; w.x=rowW[4*q+0]; w.y=rowW[4*q+1]; w.z=rowW[4*q+2]; w.w=rowW[4*q+3];
        *(float4*)&dst[4*q] = w;               // pads stay within this row
      }
    }
  }
}

// ---- blocked Cholesky, n=128, BS=16; diag slots end up holding Linv ----
__device__ void chol_factor(float* tri, int t, int lane, int wid){
  for (int kb=0; kb<8; ++kb){
    const int c0 = kb*16;
    if (wid==(kb&3)) chol_diag_gj(tri, c0, lane);
    __syncthreads();
    const int rem = 112 - c0;
    if (t < rem){                        // panel: X = A * Linv^T (dot products)
      const int r = c0+16+t;
      const int rb = rowStart(r)+c0;
      float a[16];
      #pragma unroll
      for (int q=0;q<4;++q){
        float4 w = *(const float4*)&tri[rb+4*q];
        a[4*q+0]=w.x; a[4*q+1]=w.y; a[4*q+2]=w.z; a[4*q+3]=w.w;
      }
      float x[16];
      #pragma unroll
      for (int c=0;c<16;++c){
        float acc=0.f;
        const int lb = rowStart(c0+c)+c0;
        #pragma unroll
        for (int q=0;q<=(c>>2);++q){
          float4 w = *(const float4*)&tri[lb+4*q];
          if (4*q+0<=c) acc = fmaf(w.x, a[4*q+0], acc);
          if (4*q+1<=c) acc = fmaf(w.y, a[4*q+1], acc);
          if (4*q+2<=c) acc = fmaf(w.z, a[4*q+2], acc);
          if (4*q+3<=c) acc = fmaf(w.w, a[4*q+3], acc);
        }
        x[c]=acc;
      }
      #pragma unroll
      for (int q=0;q<4;++q){
        float4 w; w.x=x[4*q+0]; w.y=x[4*q+1]; w.z=x[4*q+2]; w.w=x[4*q+3];
        *(float4*)&tri[rb+4*q] = w;
      }
    }
    __syncthreads();
    if (rem > 0){                        // trailing update, 4x4 k-chunked
      const int base = c0+16;
      const int R = rem>>2;
      const int ntile = (R*(R+1))>>1;
      for (int idx=t; idx<ntile; idx+=256){
        int I = rowOfIdx(idx);
        int J = idx - ROFF(I);
        int i0 = base + 4*I, j0 = base + 4*J;
        int ra0=rowStart(i0+0)+c0, ra1=rowStart(i0+1)+c0,
            ra2=rowStart(i0+2)+c0, ra3=rowStart(i0+3)+c0;
        int rb0=rowStart(j0+0)+c0, rb1=rowStart(j0+1)+c0,
            rb2=rowStart(j0+2)+c0, rb3=rowStart(j0+3)+c0;
        float acc[4][4];
        #pragma unroll
        for (int ii=0;ii<4;++ii)
          #pragma unroll
          for (int jj=0;jj<4;++jj) acc[ii][jj]=0.f;
        #pragma unroll
        for (int q=0;q<4;++q){
          float4 A0=*(const float4*)&tri[ra0+4*q];
          float4 A1=*(const float4*)&tri[ra1+4*q];
          float4 A2=*(const float4*)&tri[ra2+4*q];
          float4 A3=*(const float4*)&tri[ra3+4*q];
          float4 B0=*(const float4*)&tri[rb0+4*q];
          float4 B1=*(const float4*)&tri[rb1+4*q];
          float4 B2=*(const float4*)&tri[rb2+4*q];
          float4 B3=*(const float4*)&tri[rb3+4*q];
          #define DOT4(Ai,Bj) (fmaf(Ai.x,Bj.x,fmaf(Ai.y,Bj.y,fmaf(Ai.z,Bj.z,Ai.w*Bj.w))))
          acc[0][0]+=DOT4(A0,B0); acc[0][1]+=DOT4(A0,B1); acc[0][2]+=DOT4(A0,B2); acc[0][3]+=DOT4(A0,B3);
          acc[1][0]+=DOT4(A1,B0); acc[1][1]+=DOT4(A1,B1); acc[1][2]+=DOT4(A1,B2); acc[1][3]+=DOT4(A1,B3);
          acc[2][0]+=DOT4(A2,B0); acc[2][1]+=DOT4(A2,B1); acc[2][2]+=DOT4(A2,B2); acc[2][3]+=DOT4(A2,B3);
          acc[3][0]+=DOT4(A3,B0); acc[3][1]+=DOT4(A3,B1); acc[3][2]+=DOT4(A3,B2); acc[3][3]+=DOT4(A3,B3);
          #undef DOT4
        }
        #pragma unroll
        for (int ii=0;ii<4;++ii){
          #pragma unroll
          for (int jj=0;jj<4;++jj){
            int gi=i0+ii, gj=j0+jj;
            if (gi>=gj) tri[rowStart(gi)+gj] -= acc[ii][jj];
          }
        }
      }
    }
    __syncthreads();
  }
}

// forward (L y = rhs) then backward (L^T x = y), in place; diag slots hold Linv
__device__ void tri_solve_fb(const float* tri, float* rhs, int t, int lane, int wid){
  for (int kb=0;kb<8;++kb){
    const int c0=kb*16;
    if (wid==(kb&3) && lane<16){         // y_blk = Linv * r_blk  (parallel dots)
      const int c = lane;
      float v = rhs[c0+c];
      float acc = 0.f;
      const int lb = rowStart(c0+c)+c0;
      #pragma unroll
      for (int cp=0;cp<16;++cp){
        float rcp = __shfl(v, cp, 64);
        if (cp<=c) acc = fmaf(tri[lb+cp], rcp, acc);
      }
      rhs[c0+c] = acc;
    }
    __syncthreads();
    const int rem = 112-c0;
    if (t<rem){
      const int r = c0+16+t;
      const int rb = rowStart(r)+c0;
      float acc = rhs[r];
      #pragma unroll
      for (int q=0;q<4;++q){
        float4 w = *(const float4*)&tri[rb+4*q];
        acc = fmaf(-w.x, rhs[c0+4*q+0], acc);
        acc = fmaf(-w.y, rhs[c0+4*q+1], acc);
        acc = fmaf(-w.z, rhs[c0+4*q+2], acc);
        acc = fmaf(-w.w, rhs[c0+4*q+3], acc);
      }
      rhs[r] = acc;
    }
    __syncthreads();
  }
  for (int kb=7;kb>=0;--kb){
    const int c0=kb*16;
    if (wid==(kb&3) && lane<16){         // x_blk = Linv^T * r_blk
      const int c = lane;
      float v = rhs[c0+c];
      float acc = 0.f;
      #pragma unroll
      for (int cp=0;cp<16;++cp){
        float rcp = __shfl(v, cp, 64);
        if (cp>=c) acc = fmaf(tri[rowStart(c0+cp)+c0+c], rcp, acc);
      }
      rhs[c0+c] = acc;
    }
    __syncthreads();
    if (t<c0){
      float acc = rhs[t];
      #pragma unroll
      for (int c=0;c<16;++c) acc = fmaf(-tri[rowStart(c0+c)+t], rhs[c0+c], acc);
      rhs[t]=acc;
    }
    __syncthreads();
  }
}

// y[r] = sum_j mat[j*128+r] * x[j]
// MODE 0: out=sum ; MODE 1: out = -(e1+e2)+sum ; MODE 2: out = e1 - sum
template<int MODE>
__device__ __forceinline__ void matvecB(const float* __restrict__ mat,
                                        const float* __restrict__ xin,
                                        float* __restrict__ out,
                                        const float* __restrict__ e1,
                                        const float* __restrict__ e2,
                                        float* part, int t){
  const int r = t & 127;
  const int hf = t >> 7;
  const float* mp = mat + (hf<<6)*128 + r;
  const float* xp = xin + (hf<<6);
  float a0=0.f,a1=0.f,a2=0.f,a3=0.f;
  #pragma unroll
  for (int j=0;j<64;j+=4){
    a0 = fmaf(mp[(j+0)*128], xp[j+0], a0);
    a1 = fmaf(mp[(j+1)*128], xp[j+1], a1);
    a2 = fmaf(mp[(j+2)*128], xp[j+2], a2);
    a3 = fmaf(mp[(j+3)*128], xp[j+3], a3);
  }
  part[t] = (a0+a1)+(a2+a3);
  __syncthreads();
  if (t<128){
    float ssum = part[r] + part[r+128];
    if (MODE==0)      out[r] = ssum;
    else if (MODE==1) out[r] = -(e1[r]+e2[r]) + ssum;
    else              out[r] = e1[r] - ssum;
  }
  __syncthreads();
}

// ---- precompute: chol(Q), then Qi = Q^{-1} and M1 = Qi G^T ----
__global__ __launch_bounds__(256) void k_prep(const float* __restrict__ Q,
        const float* __restrict__ Gm, float* __restrict__ Qi, float* __restrict__ M1)
{
  __shared__ __align__(16) float tri[TRI_SZ];
  __shared__ float Xl[128*32];
  const int t = threadIdx.x;
  const int lane = t&63, wid = t>>6;
  for (int idx=t; idx<8256; idx+=256){
    int i = rowOfIdx(idx); int j = idx - ROFF(i);
    tri[rowStart(i)+j] = Q[i*128+j];
  }
  __syncthreads();
  chol_factor(tri, t, lane, wid);
  for (int cc=0; cc<8; ++cc){
    const int a0 = (cc&3)*32;
    const bool ident = (cc<4);
    for (int idx=t; idx<4096; idx+=256){
      int i=idx>>5, j=idx&31;
      Xl[idx] = ident ? ((i==(a0+j))?1.f:0.f) : Gm[(a0+j)*128+i];
    }
    __syncthreads();
    for (int kb=0;kb<8;++kb){                    // forward: X := L^{-1} X
      const int c0=kb*16;
      if (t<32){
        float v[16], x[16];
        #pragma unroll
        for (int c=0;c<16;++c) v[c]=Xl[(c0+c)*32+t];
        #pragma unroll
        for (int c=0;c<16;++c){
          float acc=0.f;
          const int lb=rowStart(c0+c)+c0;
          #pragma unroll
          for (int cp=0;cp<16;++cp) if (cp<=c) acc=fmaf(tri[lb+cp], v[cp], acc);
          x[c]=acc;
        }
        #pragma unroll
        for (int c=0;c<16;++c) Xl[(c0+c)*32+t]=x[c];
      }
      __syncthreads();
      const int rem=112-c0;
      for (int rr=(t>>5); rr<rem; rr+=8){
        const int r=c0+16+rr, j=t&31;
        float acc=Xl[r*32+j];
        #pragma unroll
        for (int c=0;c<16;++c) acc = fmaf(-tri[rowStart(r)+c0+c], Xl[(c0+c)*32+j], acc);
        Xl[r*32+j]=acc;
      }
      __syncthreads();
    }
    for (int kb=7;kb>=0;--kb){                   // backward: X := L^{-T} X
      const int c0=kb*16;
      if (t<32){
        float v[16], x[16];
        #pragma unroll
        for (int c=0;c<16;++c) v[c]=Xl[(c0+c)*32+t];
        #pragma unroll
        for (int c=0;c<16;++c){
          float acc=0.f;
          #pragma unroll
          for (int cp=0;cp<16;++cp) if (cp>=c) acc=fmaf(tri[rowStart(c0+cp)+c0+c], v[cp], acc);
          x[c]=acc;
        }
        #pragma unroll
        for (int c=0;c<16;++c) Xl[(c0+c)*32+t]=x[c];
      }
      __syncthreads();
      for (int rr=(t>>5); rr<c0; rr+=8){
        const int j=t&31;
        float acc=Xl[rr*32+j];
        #pragma unroll
        for (int c=0;c<16;++c) acc = fmaf(-tri[rowStart(c0+c)+rr], Xl[(c0+c)*32+j], acc);
        Xl[rr*32+j]=acc;
      }
      __syncthreads();
    }
    float* dst = ident ? Qi : M1;
    for (int idx=t; idx<4096; idx+=256){
      int i=idx>>5, j=idx&31;
      dst[i*128+a0+j] = Xl[idx];
    }
    __syncthreads();
  }
}

// K = G * M1  (= G Qi G^T), plus its diagonal
__global__ __launch_bounds__(256) void k_kmat(const float* __restrict__ Gm,
        const float* __restrict__ M1, float* __restrict__ K, float* __restrict__ Kd){
  const int idx = blockIdx.x*256 + threadIdx.x;
  const int a = idx>>7, bcol = idx&127;
  float a0=0.f,a1=0.f,a2=0.f,a3=0.f;
  #pragma unroll
  for (int j=0;j<128;j+=4){
    a0 = fmaf(Gm[a*128+j+0], M1[(j+0)*128+bcol], a0);
    a1 = fmaf(Gm[a*128+j+1], M1[(j+1)*128+bcol], a1);
    a2 = fmaf(Gm[a*128+j+2], M1[(j+2)*128+bcol], a2);
    a3 = fmaf(Gm[a*128+j+3], M1[(j+3)*128+bcol], a3);
  }
  float acc = (a0+a1)+(a2+a3);
  K[idx] = acc;
  if (a==bcol) Kd[a]=acc;
}

// ---- main: one block per batch, 20 IPM iterations ----
__global__ __launch_bounds__(256) void k_ipm(
      const float* __restrict__ G, const float* __restrict__ p,
      const float* __restrict__ h, const float* __restrict__ Qi,
      const float* __restrict__ M1, const float* __restrict__ K,
      const float* __restrict__ Kd, float* __restrict__ Z)
{
  __shared__ __align__(16) float tri[TRI_SZ];
  __shared__ float sh_z[128], sh_s[128], sh_lam[128], sh_gz[128], sh_qz[128];
  __shared__ float sh_wm[128];
  __shared__ float sh_rhs[128], sh_t[128], sh_v[128], sh_dz[128];
  __shared__ float sh_p[128], sh_h[128], sh_Kd[128], sh_scl[128];
  __shared__ float part[256];
  __shared__ float red[4];
  const int t = threadIdx.x, b = blockIdx.x;
  const int lane = t & 63, wid = t >> 6;

  if (t<128){
    sh_z[t]=0.f; sh_gz[t]=0.f; sh_qz[t]=0.f; sh_s[t]=1.f; sh_lam[t]=1.f;
    sh_p[t]=p[b*128+t]; sh_h[t]=h[t]; sh_Kd[t]=Kd[t];
  }
  __syncthreads();

  for (int it=0; it<20; ++it){
    float s_t=0.f, lam_t=0.f, rp_t=0.f, prod=0.f;
    if (t<128){
      s_t = sh_s[t]; lam_t = sh_lam[t];
      rp_t = sh_gz[t] + s_t - sh_h[t];       // r_p = Gz + s - h (Gz maintained)
      prod = s_t*lam_t;
    }
    prod = waveReduceSum(prod);
    if (lane==0) red[wid]=prod;
    __syncthreads();
    const float mu = (red[0]+red[1]+red[2]+red[3]) * (1.f/128.f);
    float rc_t=0.f, dinv_t=0.f;
    if (t<128){
      rc_t = s_t*lam_t - 0.1f*mu;            // r_c = s.lam - sigma*mu
      dinv_t = fminf(s_t/lam_t, 1e30f);      // D^{-1}, overflow-guarded
      float w = (rc_t - lam_t*rp_t)/s_t;
      sh_wm[t] = w - lam_t;
      sh_scl[t] = rsqrtf(sh_Kd[t] + dinv_t); // equilibration scale
    }
    __syncthreads();
    // rhs = -(qz+p) + G^T (w - lam)   (qz maintained incrementally)
    matvecB<1>(G, sh_wm, sh_rhs, sh_qz, sh_p, part, t);
    // tvec = G Qi rhs  (via M1 = Qi G^T)
    matvecB<0>(M1, sh_rhs, sh_t, nullptr, nullptr, part, t);
    // equilibrated A' = S(Dinv+K)S (unit diag), scale rhs
    if (t<128) sh_t[t] *= sh_scl[t];
    for (int idx=t; idx<8256; idx+=256){
      int i = rowOfIdx(idx);
      int j = idx - ROFF(i);
      tri[rowStart(i)+j] = (i==j) ? 1.0f : K[i*128+j]*sh_scl[i]*sh_scl[j];
    }
    __syncthreads();
    chol_factor(tri, t, lane, wid);
    tri_solve_fb(tri, sh_t, t, lane, wid);
    if (t<128) sh_t[t] *= sh_scl[t];         // y = S y'
    __syncthreads();
    float gdz_t=0.f, ds_t=0.f, dlam_t=0.f;
    if (t<128){
      float y = sh_t[t];
      gdz_t = dinv_t*y;                      // G dz = Dinv .* y (Woodbury identity)
      ds_t = -rp_t - gdz_t;
      dlam_t = (-rc_t - lam_t*ds_t)/s_t;
    }
    // v = rhs - G^T y ;  dz = Qi v ;  note Q dz == v (used for qz update)
    matvecB<2>(G, sh_t, sh_v, sh_rhs, nullptr, part, t);
    matvecB<0>(Qi, sh_v, sh_dz, nullptr, nullptr, part, t);
    // fraction-to-boundary step
    float ra = 1e9f;
    if (t<128){
      if (ds_t   < 0.f) ra = -s_t/ds_t;
      if (dlam_t < 0.f) ra = fminf(ra, -lam_t/dlam_t);
    }
    ra = waveReduceMin(ra);
    if (lane==0) red[wid]=ra;
    __syncthreads();
    const float rmin = fminf(fminf(red[0],red[1]), fminf(red[2],red[3]));
    const float alpha = fminf(1.0f, 0.99f*rmin);
    if (t<128){
      sh_z[t]  += alpha*sh_dz[t];
      sh_s[t]   = s_t + alpha*ds_t;
      sh_lam[t] = lam_t + alpha*dlam_t;
      sh_gz[t] += alpha*gdz_t;               // Gz incremental
      sh_qz[t] += alpha*sh_v[t];             // Qz incremental (Q dz == v)
    }
    __syncthreads();
  }
  if (t<128) Z[b*128+t] = sh_z[t];
}

// out = log_softmax(Z.reshape(10, 32768), axis=1)
__global__ __launch_bounds__(1024) void k_logsoftmax(const float* __restrict__ Z,
                                                     float* __restrict__ out){
  __shared__ float red[16];
  __shared__ float sval[2];
  const int r = blockIdx.x, t = threadIdx.x;
  const float* zp = Z + (size_t)r*32768;
  float m = -1e30f;
  for (int i=t;i<32768;i+=1024) m = fmaxf(m, zp[i]);
  #pragma unroll
  for (int o=32;o>0;o>>=1) m = fmaxf(m, __shfl_down(m,o,64));
  if ((t&63)==0) red[t>>6] = m;
  __syncthreads();
  if (t==0){ float mm=red[0]; for (int w=1;w<16;++w) mm=fmaxf(mm,red[w]); sval[0]=mm; }
  __syncthreads();
  const float mx = sval[0];
  float s=0.f;
  for (int i=t;i<32768;i+=1024) s += expf(zp[i]-mx);
  #pragma unroll
  for (int o=32;o>0;o>>=1) s += __shfl_down(s,o,64);
  if ((t&63)==0) red[t>>6]=s;
  __syncthreads();
  if (t==0){ float ss=0.f; for (int w=0;w<16;++w) ss+=red[w]; sval[1]=logf(ss); }
  __syncthreads();
  const float lse = sval[1];
  for (int i=t;i<32768;i+=1024) out[(size_t)r*32768+i] = zp[i]-mx-lse;
}

extern "C" void kernel_launch(void* const* d_in, const int* in_sizes, int n_in,
                              void* d_out, int out_size, void* d_ws, size_t ws_size,
                              hipStream_t stream){
  // inputs: 0=x (unused), 1=Q[128x128], 2=p[2560x128], 3=G[128x128], 4=h[128], 5=m
  const float* Q = (const float*)d_in[1];
  const float* p = (const float*)d_in[2];
  const float* G = (const float*)d_in[3];
  const float* h = (const float*)d_in[4];
  float* ws = (float*)d_ws;
  float* Z  = ws;                 // 327680
  float* Qi = Z + 327680;         // 16384
  float* M1 = Qi + 16384;         // 16384
  float* K  = M1 + 16384;         // 16384
  float* Kd = K + 16384;          // 128
  float* out = (float*)d_out;

  hipLaunchKernelGGL(k_prep, dim3(1), dim3(256), 0, stream, Q, G, Qi, M1);
  hipLaunchKernelGGL(k_kmat, dim3(64), dim3(256), 0, stream, G, M1, K, Kd);
  hipLaunchKernelGGL(k_ipm,  dim3(2560), dim3(256), 0, stream,
                     G, p, h, Qi, M1, K, Kd, Z);
  hipLaunchKernelGGL(k_logsoftmax, dim3(10), dim3(1024), 0, stream, Z, out);
}

// Round 5
// 19755.605 us; speedup vs baseline: 1.6917x; 1.0042x over previous
//
#include <hip/hip_runtime.h>
#include <math.h>

// OptNet IPM QP solve via Woodbury, Round 5: split megakernel.
//  M = Q + G^T D G;  M^{-1} = Qi - Qi G^T (Dinv + K)^{-1} G Qi,  K = G Qi G^T
// Per iteration (20x): k_B (stage1 + rhs/tv GEMMs, 80 blocks), k_C (per-batch
// Cholesky solve + step + s/lam/gz update, 2560 blocks), k_D (v/dz GEMMs +
// z/qz update, 80 blocks). State arrays stored n-major [i][B] (B=2560) so GEMM
// tiles and k_C column reads are coalesced/L2-friendly. Small kernels allocate
// registers cleanly -> no scratch spills (round 2-4 killer).

#define B_TOT 2560
#define TB 32
#define NB (B_TOT/TB)

__device__ __forceinline__ int ROFF(int i){ return (i*(i+1))>>1; }
// padded-row packed lower triangle: row i starts at rowStart(i), 16B aligned
__device__ __forceinline__ int rowStart(int i){
  int a=i>>2, b=i&3;
  return ((a+1)*((a<<1)+b))<<2;
}
#define TRI_SZ 8448

__device__ __forceinline__ float waveReduceSum(float v){
  #pragma unroll
  for (int o=32;o>0;o>>=1) v += __shfl_down(v,o,64);
  return v;
}
__device__ __forceinline__ float waveReduceMin(float v){
  #pragma unroll
  for (int o=32;o>0;o>>=1) v = fminf(v, __shfl_down(v,o,64));
  return v;
}
__device__ __forceinline__ int rowOfIdx(int idx){
  int i = (int)((sqrtf(8.f*(float)idx+1.f)-1.f)*0.5f);
  while (((i+1)*(i+2)>>1) <= idx) ++i;
  while (((i*(i+1))>>1) > idx) --i;
  return i;
}

// ---- Gauss-Jordan 16x16 diag block: factor AND invert (one wave) ----
__device__ __forceinline__ void chol_diag_gj(float* tri, int c0, int lane){
  float rowA[16], rowW[16];
  const int r = lane;
  #pragma unroll
  for (int j=0;j<16;++j){ rowA[j]=0.f; rowW[j]=0.f; }
  if (r < 16){
    const float* src = &tri[rowStart(c0+r)+c0];
    #pragma unroll
    for (int q=0;q<4;++q){
      if (q <= (r>>2)){
        float4 w = *(const float4*)&src[4*q];
        rowA[4*q+0]=w.x; rowA[4*q+1]=w.y; rowA[4*q+2]=w.z; rowA[4*q+3]=w.w;
      }
    }
    #pragma unroll
    for (int j=0;j<16;++j) if (j>r) rowA[j]=0.f;
    #pragma unroll
    for (int j=0;j<16;++j) rowW[j] = (j==r)?1.f:0.f;
  }
  #pragma unroll
  for (int k=0;k<16;++k){
    float akk = __shfl(rowA[k], k, 64);
    akk = fmaxf(akk, 1e-12f);
    float linv = rsqrtf(akk);
    linv = linv*(1.5f - 0.5f*akk*linv*linv);   // Newton step
    float lrk = rowA[k]*linv;                  // valid for r>=k
    if (r==k){
      #pragma unroll
      for (int c=0;c<16;++c) rowW[c] *= linv;  // final Linv row k
    }
    #pragma unroll
    for (int j=k+1;j<16;++j){
      float ljk = __shfl(lrk, j, 64);
      if (r>=j) rowA[j] = fmaf(-lrk, ljk, rowA[j]);
    }
    #pragma unroll
    for (int c=0;c<=k;++c){
      float wkc = __shfl(rowW[c], k, 64);
      if (r>k) rowW[c] = fmaf(-lrk, wkc, rowW[c]);
    }
  }
  if (r < 16){
    float* dst = &tri[rowStart(c0+r)+c0];
    #pragma unroll
    for (int q=0;q<4;++q){
      if (q <= (r>>2)){
        float4 w; w.x=rowW[4*q+0]; w.y=rowW[4*q+1]; w.z=rowW[4*q+2]; w.w=rowW[4*q+3];
        *(float4*)&dst[4*q] = w;
      }
    }
  }
}

// ---- blocked Cholesky, n=128, BS=16; diag slots end up holding Linv ----
__device__ void chol_factor(float* tri, int t, int lane, int wid){
  for (int kb=0; kb<8; ++kb){
    const int c0 = kb*16;
    if (wid==(kb&3)) chol_diag_gj(tri, c0, lane);
    __syncthreads();
    const int rem = 112 - c0;
    if (t < rem){                        // panel: X = A * Linv^T (dot products)
      const int r = c0+16+t;
      const int rb = rowStart(r)+c0;
      float a[16];
      #pragma unroll
      for (int q=0;q<4;++q){
        float4 w = *(const float4*)&tri[rb+4*q];
        a[4*q+0]=w.x; a[4*q+1]=w.y; a[4*q+2]=w.z; a[4*q+3]=w.w;
      }
      float x[16];
      #pragma unroll
      for (int c=0;c<16;++c){
        float acc=0.f;
        const int lb = rowStart(c0+c)+c0;
        #pragma unroll
        for (int q=0;q<=(c>>2);++q){
          float4 w = *(const float4*)&tri[lb+4*q];
          if (4*q+0<=c) acc = fmaf(w.x, a[4*q+0], acc);
          if (4*q+1<=c) acc = fmaf(w.y, a[4*q+1], acc);
          if (4*q+2<=c) acc = fmaf(w.z, a[4*q+2], acc);
          if (4*q+3<=c) acc = fmaf(w.w, a[4*q+3], acc);
        }
        x[c]=acc;
      }
      #pragma unroll
      for (int q=0;q<4;++q){
        float4 w; w.x=x[4*q+0]; w.y=x[4*q+1]; w.z=x[4*q+2]; w.w=x[4*q+3];
        *(float4*)&tri[rb+4*q] = w;
      }
    }
    __syncthreads();
    if (rem > 0){                        // trailing update, 4x4 k-chunked
      const int base = c0+16;
      const int R = rem>>2;
      const int ntile = (R*(R+1))>>1;
      for (int idx=t; idx<ntile; idx+=256){
        int I = rowOfIdx(idx);
        int J = idx - ROFF(I);
        int i0 = base + 4*I, j0 = base + 4*J;
        int ra0=rowStart(i0+0)+c0, ra1=rowStart(i0+1)+c0,
            ra2=rowStart(i0+2)+c0, ra3=rowStart(i0+3)+c0;
        int rb0=rowStart(j0+0)+c0, rb1=rowStart(j0+1)+c0,
            rb2=rowStart(j0+2)+c0, rb3=rowStart(j0+3)+c0;
        float acc[4][4];
        #pragma unroll
        for (int ii=0;ii<4;++ii)
          #pragma unroll
          for (int jj=0;jj<4;++jj) acc[ii][jj]=0.f;
        #pragma unroll
        for (int q=0;q<4;++q){
          float4 A0=*(const float4*)&tri[ra0+4*q];
          float4 A1=*(const float4*)&tri[ra1+4*q];
          float4 A2=*(const float4*)&tri[ra2+4*q];
          float4 A3=*(const float4*)&tri[ra3+4*q];
          float4 B0=*(const float4*)&tri[rb0+4*q];
          float4 B1=*(const float4*)&tri[rb1+4*q];
          float4 B2=*(const float4*)&tri[rb2+4*q];
          float4 B3=*(const float4*)&tri[rb3+4*q];
          #define DOT4(Ai,Bj) (fmaf(Ai.x,Bj.x,fmaf(Ai.y,Bj.y,fmaf(Ai.z,Bj.z,Ai.w*Bj.w))))
          acc[0][0]+=DOT4(A0,B0); acc[0][1]+=DOT4(A0,B1); acc[0][2]+=DOT4(A0,B2); acc[0][3]+=DOT4(A0,B3);
          acc[1][0]+=DOT4(A1,B0); acc[1][1]+=DOT4(A1,B1); acc[1][2]+=DOT4(A1,B2); acc[1][3]+=DOT4(A1,B3);
          acc[2][0]+=DOT4(A2,B0); acc[2][1]+=DOT4(A2,B1); acc[2][2]+=DOT4(A2,B2); acc[2][3]+=DOT4(A2,B3);
          acc[3][0]+=DOT4(A3,B0); acc[3][1]+=DOT4(A3,B1); acc[3][2]+=DOT4(A3,B2); acc[3][3]+=DOT4(A3,B3);
          #undef DOT4
        }
        #pragma unroll
        for (int ii=0;ii<4;++ii){
          #pragma unroll
          for (int jj=0;jj<4;++jj){
            int gi=i0+ii, gj=j0+jj;
            if (gi>=gj) tri[rowStart(gi)+gj] -= acc[ii][jj];
          }
        }
      }
    }
    __syncthreads();
  }
}

// forward (L y = rhs) then backward (L^T x = y), in place; diag slots hold Linv
__device__ void tri_solve_fb(const float* tri, float* rhs, int t, int lane, int wid){
  for (int kb=0;kb<8;++kb){
    const int c0=kb*16;
    if (wid==(kb&3) && lane<16){
      const int c = lane;
      float v = rhs[c0+c];
      float acc = 0.f;
      const int lb = rowStart(c0+c)+c0;
      #pragma unroll
      for (int cp=0;cp<16;++cp){
        float rcp = __shfl(v, cp, 64);
        if (cp<=c) acc = fmaf(tri[lb+cp], rcp, acc);
      }
      rhs[c0+c] = acc;
    }
    __syncthreads();
    const int rem = 112-c0;
    if (t<rem){
      const int r = c0+16+t;
      const int rb = rowStart(r)+c0;
      float acc = rhs[r];
      #pragma unroll
      for (int q=0;q<4;++q){
        float4 w = *(const float4*)&tri[rb+4*q];
        acc = fmaf(-w.x, rhs[c0+4*q+0], acc);
        acc = fmaf(-w.y, rhs[c0+4*q+1], acc);
        acc = fmaf(-w.z, rhs[c0+4*q+2], acc);
        acc = fmaf(-w.w, rhs[c0+4*q+3], acc);
      }
      rhs[r] = acc;
    }
    __syncthreads();
  }
  for (int kb=7;kb>=0;--kb){
    const int c0=kb*16;
    if (wid==(kb&3) && lane<16){
      const int c = lane;
      float v = rhs[c0+c];
      float acc = 0.f;
      #pragma unroll
      for (int cp=0;cp<16;++cp){
        float rcp = __shfl(v, cp, 64);
        if (cp>=c) acc = fmaf(tri[rowStart(c0+cp)+c0+c], rcp, acc);
      }
      rhs[c0+c] = acc;
    }
    __syncthreads();
    if (t<c0){
      float acc = rhs[t];
      #pragma unroll
      for (int c=0;c<16;++c) acc = fmaf(-tri[rowStart(c0+c)+t], rhs[c0+c], acc);
      rhs[t]=acc;
    }
    __syncthreads();
  }
}

// ---- precompute: chol(Q), then Qi = Q^{-1} and M1 = Qi G^T ----
__global__ __launch_bounds__(256) void k_prep(const float* __restrict__ Q,
        const float* __restrict__ Gm, float* __restrict__ Qi, float* __restrict__ M1)
{
  __shared__ __align__(16) float tri[TRI_SZ];
  __shared__ float Xl[128*32];
  const int t = threadIdx.x;
  const int lane = t&63, wid = t>>6;
  for (int idx=t; idx<8256; idx+=256){
    int i = rowOfIdx(idx); int j = idx - ROFF(i);
    tri[rowStart(i)+j] = Q[i*128+j];
  }
  __syncthreads();
  chol_factor(tri, t, lane, wid);
  for (int cc=0; cc<8; ++cc){
    const int a0 = (cc&3)*32;
    const bool ident = (cc<4);
    for (int idx=t; idx<4096; idx+=256){
      int i=idx>>5, j=idx&31;
      Xl[idx] = ident ? ((i==(a0+j))?1.f:0.f) : Gm[(a0+j)*128+i];
    }
    __syncthreads();
    for (int kb=0;kb<8;++kb){                    // forward: X := L^{-1} X
      const int c0=kb*16;
      if (t<32){
        float v[16], x[16];
        #pragma unroll
        for (int c=0;c<16;++c) v[c]=Xl[(c0+c)*32+t];
        #pragma unroll
        for (int c=0;c<16;++c){
          float acc=0.f;
          const int lb=rowStart(c0+c)+c0;
          #pragma unroll
          for (int cp=0;cp<16;++cp) if (cp<=c) acc=fmaf(tri[lb+cp], v[cp], acc);
          x[c]=acc;
        }
        #pragma unroll
        for (int c=0;c<16;++c) Xl[(c0+c)*32+t]=x[c];
      }
      __syncthreads();
      const int rem=112-c0;
      for (int rr=(t>>5); rr<rem; rr+=8){
        const int r=c0+16+rr, j=t&31;
        float acc=Xl[r*32+j];
        #pragma unroll
        for (int c=0;c<16;++c) acc = fmaf(-tri[rowStart(r)+c0+c], Xl[(c0+c)*32+j], acc);
        Xl[r*32+j]=acc;
      }
      __syncthreads();
    }
    for (int kb=7;kb>=0;--kb){                   // backward: X := L^{-T} X
      const int c0=kb*16;
      if (t<32){
        float v[16], x[16];
        #pragma unroll
        for (int c=0;c<16;++c) v[c]=Xl[(c0+c)*32+t];
        #pragma unroll
        for (int c=0;c<16;++c){
          float acc=0.f;
          #pragma unroll
          for (int cp=0;cp<16;++cp) if (cp>=c) acc=fmaf(tri[rowStart(c0+cp)+c0+c], v[cp], acc);
          x[c]=acc;
        }
        #pragma unroll
        for (int c=0;c<16;++c) Xl[(c0+c)*32+t]=x[c];
      }
      __syncthreads();
      for (int rr=(t>>5); rr<c0; rr+=8){
        const int j=t&31;
        float acc=Xl[rr*32+j];
        #pragma unroll
        for (int c=0;c<16;++c) acc = fmaf(-tri[rowStart(c0+c)+rr], Xl[(c0+c)*32+j], acc);
        Xl[rr*32+j]=acc;
      }
      __syncthreads();
    }
    float* dst = ident ? Qi : M1;
    for (int idx=t; idx<4096; idx+=256){
      int i=idx>>5, j=idx&31;
      dst[i*128+a0+j] = Xl[idx];
    }
    __syncthreads();
  }
}

// K = G * M1  (= G Qi G^T), plus its diagonal
__global__ __launch_bounds__(256) void k_kmat(const float* __restrict__ Gm,
        const float* __restrict__ M1, float* __restrict__ K, float* __restrict__ Kd){
  const int idx = blockIdx.x*256 + threadIdx.x;
  const int a = idx>>7, bcol = idx&127;
  float a0=0.f,a1=0.f,a2=0.f,a3=0.f;
  #pragma unroll
  for (int j=0;j<128;j+=4){
    a0 = fmaf(Gm[a*128+j+0], M1[(j+0)*128+bcol], a0);
    a1 = fmaf(Gm[a*128+j+1], M1[(j+1)*128+bcol], a1);
    a2 = fmaf(Gm[a*128+j+2], M1[(j+2)*128+bcol], a2);
    a3 = fmaf(Gm[a*128+j+3], M1[(j+3)*128+bcol], a3);
  }
  float acc = (a0+a1)+(a2+a3);
  K[idx] = acc;
  if (a==bcol) Kd[a]=acc;
}

// ---- init: state arrays + p transpose (n-major) ----
__global__ __launch_bounds__(256) void k_init(const float* __restrict__ p,
    float* __restrict__ Pt, float* __restrict__ S, float* __restrict__ LAM,
    float* __restrict__ GZ, float* __restrict__ QZ, float* __restrict__ Zst){
  int idx = blockIdx.x*256 + threadIdx.x;
  if (idx < 128*B_TOT){
    int i = idx/B_TOT, b = idx - i*B_TOT;
    Pt[idx] = p[b*128+i];
    S[idx]=1.f; LAM[idx]=1.f; GZ[idx]=0.f; QZ[idx]=0.f; Zst[idx]=0.f;
  }
}

// ---- k_B: stage1 + rhs = -(qz+p)+G^T wm ; tv = G Qi rhs (via M1^T) ----
__global__ __launch_bounds__(256) void k_B(const float* __restrict__ G,
    const float* __restrict__ M1, const float* __restrict__ Pt,
    const float* __restrict__ h,
    const float* __restrict__ S, const float* __restrict__ LAM,
    const float* __restrict__ GZ, const float* __restrict__ QZ,
    float* __restrict__ RHS, float* __restrict__ TV){
  __shared__ float wm_l[128*33];
  __shared__ float rhs_l[128*33];
  __shared__ float part_l[8*33];
  __shared__ float mu_l[TB];
  __shared__ float h_l[128];
  const int t=threadIdx.x, g=t>>5, bl=t&31;
  const int b = blockIdx.x*TB + bl;
  if (t<128) h_l[t]=h[t];
  __syncthreads();
  float sv[16], lv[16], rpv[16];
  float prod=0.f;
  #pragma unroll
  for (int q=0;q<16;++q){
    int i = g + 8*q;
    float s = S[i*B_TOT+b], l = LAM[i*B_TOT+b], gz = GZ[i*B_TOT+b];
    sv[q]=s; lv[q]=l; rpv[q]=gz+s-h_l[i];
    prod += s*l;
  }
  part_l[g*33+bl] = prod;
  __syncthreads();
  if (g==0){
    float m=0.f;
    #pragma unroll
    for (int q=0;q<8;++q) m += part_l[q*33+bl];
    mu_l[bl] = m*(1.f/128.f);
  }
  __syncthreads();
  const float mu = mu_l[bl];
  #pragma unroll
  for (int q=0;q<16;++q){
    int i=g+8*q;
    float rc = sv[q]*lv[q] - 0.1f*mu;
    wm_l[i*33+bl] = (rc - lv[q]*rpv[q])/sv[q] - lv[q];
  }
  __syncthreads();
  const int r0 = g*16;
  float acc[16];
  #pragma unroll
  for (int q=0;q<16;++q) acc[q] = -(QZ[(r0+q)*B_TOT+b] + Pt[(r0+q)*B_TOT+b]);
  #pragma unroll 2
  for (int j=0;j<128;++j){
    float wmv = wm_l[j*33+bl];
    const float4* gp = (const float4*)&G[j*128+r0];
    #pragma unroll
    for (int q4=0;q4<4;++q4){
      float4 gv = gp[q4];
      acc[4*q4+0]=fmaf(gv.x,wmv,acc[4*q4+0]);
      acc[4*q4+1]=fmaf(gv.y,wmv,acc[4*q4+1]);
      acc[4*q4+2]=fmaf(gv.z,wmv,acc[4*q4+2]);
      acc[4*q4+3]=fmaf(gv.w,wmv,acc[4*q4+3]);
    }
  }
  #pragma unroll
  for (int q=0;q<16;++q){
    rhs_l[(r0+q)*33+bl]=acc[q];
    RHS[(r0+q)*B_TOT+b]=acc[q];
  }
  __syncthreads();
  #pragma unroll
  for (int q=0;q<16;++q) acc[q]=0.f;
  #pragma unroll 2
  for (int j=0;j<128;++j){
    float rv = rhs_l[j*33+bl];
    const float4* mp = (const float4*)&M1[j*128+r0];
    #pragma unroll
    for (int q4=0;q4<4;++q4){
      float4 mv = mp[q4];
      acc[4*q4+0]=fmaf(mv.x,rv,acc[4*q4+0]);
      acc[4*q4+1]=fmaf(mv.y,rv,acc[4*q4+1]);
      acc[4*q4+2]=fmaf(mv.z,rv,acc[4*q4+2]);
      acc[4*q4+3]=fmaf(mv.w,rv,acc[4*q4+3]);
    }
  }
  #pragma unroll
  for (int q=0;q<16;++q) TV[(r0+q)*B_TOT+b]=acc[q];
}

// ---- k_C: build S(Dinv+K)S, Cholesky, solve, step, update s/lam/gz ----
__global__ __launch_bounds__(256) void k_C(const float* __restrict__ K,
    const float* __restrict__ Kd, const float* __restrict__ h,
    const float* __restrict__ TV,
    float* __restrict__ S, float* __restrict__ LAM, float* __restrict__ GZ,
    float* __restrict__ Y, float* __restrict__ ALPHA){
  __shared__ __align__(16) float tri[TRI_SZ];
  __shared__ float scl_l[128];
  __shared__ float sh_t[128];
  __shared__ float red[4];
  const int t=threadIdx.x, b=blockIdx.x;
  const int lane=t&63, wid=t>>6;
  float s_t=0.f,lam_t=0.f,gz_t=0.f,rp_t=0.f,rc_t=0.f,dinv_t=0.f;
  float prod=0.f;
  if (t<128){
    s_t=S[t*B_TOT+b]; lam_t=LAM[t*B_TOT+b]; gz_t=GZ[t*B_TOT+b];
    rp_t = gz_t + s_t - h[t];
    prod = s_t*lam_t;
  }
  prod = waveReduceSum(prod);
  if (lane==0) red[wid]=prod;
  __syncthreads();
  const float mu = (red[0]+red[1]+red[2]+red[3])*(1.f/128.f);
  if (t<128){
    rc_t = s_t*lam_t - 0.1f*mu;
    dinv_t = fminf(s_t/lam_t, 1e30f);
    float sc = rsqrtf(Kd[t]+dinv_t);
    scl_l[t]=sc;
    sh_t[t] = TV[t*B_TOT+b]*sc;
  }
  __syncthreads();
  for (int idx=t; idx<8256; idx+=256){
    int i = rowOfIdx(idx);
    int j = idx - ROFF(i);
    tri[rowStart(i)+j] = (i==j)?1.0f : K[i*128+j]*scl_l[i]*scl_l[j];
  }
  __syncthreads();
  chol_factor(tri,t,lane,wid);
  tri_solve_fb(tri,sh_t,t,lane,wid);
  float y=0.f,gdz=0.f,ds=0.f,dlam=0.f;
  float ra=1e9f;
  if (t<128){
    y = sh_t[t]*scl_l[t];
    gdz = dinv_t*y;                       // G dz = Dinv .* y (Woodbury identity)
    ds = -rp_t - gdz;
    dlam = (-rc_t - lam_t*ds)/s_t;
    if (ds<0.f)   ra = -s_t/ds;
    if (dlam<0.f) ra = fminf(ra, -lam_t/dlam);
  }
  ra = waveReduceMin(ra);
  if (lane==0) red[wid]=ra;
  __syncthreads();
  const float alpha = fminf(1.0f,
      0.99f*fminf(fminf(red[0],red[1]),fminf(red[2],red[3])));
  if (t<128){
    S[t*B_TOT+b]   = s_t + alpha*ds;
    LAM[t*B_TOT+b] = lam_t + alpha*dlam;
    GZ[t*B_TOT+b]  = gz_t + alpha*gdz;
    Y[t*B_TOT+b]   = y;
  }
  if (t==0) ALPHA[b]=alpha;
}

// ---- k_D: v = rhs - G^T y ; dz = Qi v ; z += a dz ; qz += a v ----
__global__ __launch_bounds__(256) void k_D(const float* __restrict__ G,
    const float* __restrict__ Qi, const float* __restrict__ RHS,
    const float* __restrict__ Y, const float* __restrict__ ALPHA,
    float* __restrict__ Zst, float* __restrict__ QZ){
  __shared__ float y_l[128*33];
  __shared__ float v_l[128*33];
  const int t=threadIdx.x, g=t>>5, bl=t&31;
  const int b = blockIdx.x*TB + bl;
  #pragma unroll
  for (int q=0;q<16;++q){
    int i=g+8*q;
    y_l[i*33+bl] = Y[i*B_TOT+b];
  }
  const float alpha = ALPHA[b];
  __syncthreads();
  const int r0=g*16;
  float acc[16];
  #pragma unroll
  for (int q=0;q<16;++q) acc[q]=RHS[(r0+q)*B_TOT+b];
  #pragma unroll 2
  for (int j=0;j<128;++j){
    float yv = y_l[j*33+bl];
    const float4* gp=(const float4*)&G[j*128+r0];
    #pragma unroll
    for (int q4=0;q4<4;++q4){
      float4 gv=gp[q4];
      acc[4*q4+0]=fmaf(-gv.x,yv,acc[4*q4+0]);
      acc[4*q4+1]=fmaf(-gv.y,yv,acc[4*q4+1]);
      acc[4*q4+2]=fmaf(-gv.z,yv,acc[4*q4+2]);
      acc[4*q4+3]=fmaf(-gv.w,yv,acc[4*q4+3]);
    }
  }
  #pragma unroll
  for (int q=0;q<16;++q){
    v_l[(r0+q)*33+bl]=acc[q];
    float* qp=&QZ[(r0+q)*B_TOT+b];
    *qp = *qp + alpha*acc[q];            // qz += a*v  (Q dz == v)
  }
  __syncthreads();
  #pragma unroll
  for (int q=0;q<16;++q) acc[q]=0.f;
  #pragma unroll 2
  for (int j=0;j<128;++j){
    float vv = v_l[j*33+bl];
    const float4* qp4=(const float4*)&Qi[j*128+r0];
    #pragma unroll
    for (int q4=0;q4<4;++q4){
      float4 qv=qp4[q4];
      acc[4*q4+0]=fmaf(qv.x,vv,acc[4*q4+0]);
      acc[4*q4+1]=fmaf(qv.y,vv,acc[4*q4+1]);
      acc[4*q4+2]=fmaf(qv.z,vv,acc[4*q4+2]);
      acc[4*q4+3]=fmaf(qv.w,vv,acc[4*q4+3]);
    }
  }
  #pragma unroll
  for (int q=0;q<16;++q){
    float* zp=&Zst[(r0+q)*B_TOT+b];
    *zp = *zp + alpha*acc[q];            // z += a*dz
  }
}

// out = log_softmax(Z.reshape(10, 32768), axis=1), Z stored n-major [i][B]
__global__ __launch_bounds__(1024) void k_logsoftmax(const float* __restrict__ Zst,
                                                     float* __restrict__ out){
  __shared__ float red[16];
  __shared__ float sval[2];
  const int r = blockIdx.x, t = threadIdx.x;
  float m = -1e30f;
  for (int k=t;k<32768;k+=1024){
    float v = Zst[(k&127)*B_TOT + r*256 + (k>>7)];
    m = fmaxf(m, v);
  }
  #pragma unroll
  for (int o=32;o>0;o>>=1) m = fmaxf(m, __shfl_down(m,o,64));
  if ((t&63)==0) red[t>>6] = m;
  __syncthreads();
  if (t==0){ float mm=red[0]; for (int w=1;w<16;++w) mm=fmaxf(mm,red[w]); sval[0]=mm; }
  __syncthreads();
  const float mx = sval[0];
  float s=0.f;
  for (int k=t;k<32768;k+=1024){
    float v = Zst[(k&127)*B_TOT + r*256 + (k>>7)];
    s += expf(v-mx);
  }
  #pragma unroll
  for (int o=32;o>0;o>>=1) s += __shfl_down(s,o,64);
  if ((t&63)==0) red[t>>6]=s;
  __syncthreads();
  if (t==0){ float ss=0.f; for (int w=0;w<16;++w) ss+=red[w]; sval[1]=logf(ss); }
  __syncthreads();
  const float lse = sval[1];
  for (int k=t;k<32768;k+=1024){
    float v = Zst[(k&127)*B_TOT + r*256 + (k>>7)];
    out[(size_t)r*32768+k] = v-mx-lse;
  }
}

extern "C" void kernel_launch(void* const* d_in, const int* in_sizes, int n_in,
                              void* d_out, int out_size, void* d_ws, size_t ws_size,
                              hipStream_t stream){
  // inputs: 0=x (unused), 1=Q[128x128], 2=p[2560x128], 3=G[128x128], 4=h[128], 5=m
  const float* Q = (const float*)d_in[1];
  const float* p = (const float*)d_in[2];
  const float* G = (const float*)d_in[3];
  const float* h = (const float*)d_in[4];
  float* ws  = (float*)d_ws;
  const int NE = 128*B_TOT;              // 327680
  float* Zst = ws;                       // [128][2560]
  float* Qi  = Zst + NE;                 // 16384
  float* M1  = Qi + 16384;               // 16384
  float* K   = M1 + 16384;               // 16384
  float* Kd  = K + 16384;                // 128
  float* ALPHA = Kd + 128;               // 2560
  float* Pt  = ALPHA + 2560;             // NE
  float* S   = Pt + NE;                  // NE
  float* LAM = S + NE;                   // NE
  float* GZ  = LAM + NE;                 // NE
  float* QZ  = GZ + NE;                  // NE
  float* RHS = QZ + NE;                  // NE
  float* TV  = RHS + NE;                 // NE
  float* Y   = TV + NE;                  // NE
  float* out = (float*)d_out;

  hipLaunchKernelGGL(k_prep, dim3(1), dim3(256), 0, stream, Q, G, Qi, M1);
  hipLaunchKernelGGL(k_kmat, dim3(64), dim3(256), 0, stream, G, M1, K, Kd);
  hipLaunchKernelGGL(k_init, dim3((NE+255)/256), dim3(256), 0, stream,
                     p, Pt, S, LAM, GZ, QZ, Zst);
  for (int it=0; it<20; ++it){
    hipLaunchKernelGGL(k_B, dim3(NB), dim3(256), 0, stream,
                       G, M1, Pt, h, S, LAM, GZ, QZ, RHS, TV);
    hipLaunchKernelGGL(k_C, dim3(B_TOT), dim3(256), 0, stream,
                       K, Kd, h, TV, S, LAM, GZ, Y, ALPHA);
    hipLaunchKernelGGL(k_D, dim3(NB), dim3(256), 0, stream,
                       G, Qi, RHS, Y, ALPHA, Zst, QZ);
  }
  hipLaunchKernelGGL(k_logsoftmax, dim3(10), dim3(1024), 0, stream, Zst, out);
}

// Round 6
// 10472.062 us; speedup vs baseline: 3.1914x; 1.8865x over previous
//
#include <hip/hip_runtime.h>
#include <math.h>

// OptNet IPM QP solve via Woodbury, Round 6: wave-per-batch Cholesky.
//  M = Q + G^T D G;  M^{-1} = Qi - Qi G^T (Dinv + K)^{-1} G Qi,  K = G Qi G^T
// k_C now uses 64-thread blocks (one wave = one batch): __syncthreads() in a
// single-wave workgroup is just a waitcnt (no cross-wave barrier idle), the
// serial GJ shuffle chains of 4 batches overlap across the CU's 4 SIMDs, and
// LDS (33.8 KB/batch) allows 4 blocks/CU. Same math as round 5.

#define B_TOT 2560
#define TB 32
#define NB (B_TOT/TB)

__device__ __forceinline__ int ROFF(int i){ return (i*(i+1))>>1; }
// padded-row packed lower triangle: row i starts at rowStart(i), 16B aligned
__device__ __forceinline__ int rowStart(int i){
  int a=i>>2, b=i&3;
  return ((a+1)*((a<<1)+b))<<2;
}
#define TRI_SZ 8448

__device__ __forceinline__ int rowOfIdx(int idx){
  int i = (int)((sqrtf(8.f*(float)idx+1.f)-1.f)*0.5f);
  while (((i+1)*(i+2)>>1) <= idx) ++i;
  while (((i*(i+1))>>1) > idx) --i;
  return i;
}

// ---- Gauss-Jordan 16x16 diag block: factor AND invert (lanes 0..15) ----
__device__ __forceinline__ void chol_diag_gj(float* tri, int c0, int lane){
  float rowA[16], rowW[16];
  const int r = lane;
  #pragma unroll
  for (int j=0;j<16;++j){ rowA[j]=0.f; rowW[j]=0.f; }
  if (r < 16){
    const float* src = &tri[rowStart(c0+r)+c0];
    #pragma unroll
    for (int q=0;q<4;++q){
      if (q <= (r>>2)){
        float4 w = *(const float4*)&src[4*q];
        rowA[4*q+0]=w.x; rowA[4*q+1]=w.y; rowA[4*q+2]=w.z; rowA[4*q+3]=w.w;
      }
    }
    #pragma unroll
    for (int j=0;j<16;++j) if (j>r) rowA[j]=0.f;
    #pragma unroll
    for (int j=0;j<16;++j) rowW[j] = (j==r)?1.f:0.f;
  }
  #pragma unroll
  for (int k=0;k<16;++k){
    float akk = __shfl(rowA[k], k, 64);
    akk = fmaxf(akk, 1e-12f);
    float linv = rsqrtf(akk);
    linv = linv*(1.5f - 0.5f*akk*linv*linv);   // Newton step
    float lrk = rowA[k]*linv;                  // valid for r>=k
    if (r==k){
      #pragma unroll
      for (int c=0;c<16;++c) rowW[c] *= linv;  // final Linv row k
    }
    #pragma unroll
    for (int j=k+1;j<16;++j){
      float ljk = __shfl(lrk, j, 64);
      if (r>=j) rowA[j] = fmaf(-lrk, ljk, rowA[j]);
    }
    #pragma unroll
    for (int c=0;c<=k;++c){
      float wkc = __shfl(rowW[c], k, 64);
      if (r>k) rowW[c] = fmaf(-lrk, wkc, rowW[c]);
    }
  }
  if (r < 16){
    float* dst = &tri[rowStart(c0+r)+c0];
    #pragma unroll
    for (int q=0;q<4;++q){
      if (q <= (r>>2)){
        float4 w; w.x=rowW[4*q+0]; w.y=rowW[4*q+1]; w.z=rowW[4*q+2]; w.w=rowW[4*q+3];
        *(float4*)&dst[4*q] = w;
      }
    }
  }
}

// ---- 256-thread blocked Cholesky (used by k_prep only) ----
__device__ void chol_factor(float* tri, int t, int lane, int wid){
  for (int kb=0; kb<8; ++kb){
    const int c0 = kb*16;
    if (wid==(kb&3)) chol_diag_gj(tri, c0, lane);
    __syncthreads();
    const int rem = 112 - c0;
    if (t < rem){
      const int r = c0+16+t;
      const int rb = rowStart(r)+c0;
      float a[16];
      #pragma unroll
      for (int q=0;q<4;++q){
        float4 w = *(const float4*)&tri[rb+4*q];
        a[4*q+0]=w.x; a[4*q+1]=w.y; a[4*q+2]=w.z; a[4*q+3]=w.w;
      }
      float x[16];
      #pragma unroll
      for (int c=0;c<16;++c){
        float acc=0.f;
        const int lb = rowStart(c0+c)+c0;
        #pragma unroll
        for (int q=0;q<=(c>>2);++q){
          float4 w = *(const float4*)&tri[lb+4*q];
          if (4*q+0<=c) acc = fmaf(w.x, a[4*q+0], acc);
          if (4*q+1<=c) acc = fmaf(w.y, a[4*q+1], acc);
          if (4*q+2<=c) acc = fmaf(w.z, a[4*q+2], acc);
          if (4*q+3<=c) acc = fmaf(w.w, a[4*q+3], acc);
        }
        x[c]=acc;
      }
      #pragma unroll
      for (int q=0;q<4;++q){
        float4 w; w.x=x[4*q+0]; w.y=x[4*q+1]; w.z=x[4*q+2]; w.w=x[4*q+3];
        *(float4*)&tri[rb+4*q] = w;
      }
    }
    __syncthreads();
    if (rem > 0){
      const int base = c0+16;
      const int R = rem>>2;
      const int ntile = (R*(R+1))>>1;
      for (int idx=t; idx<ntile; idx+=256){
        int I = rowOfIdx(idx);
        int J = idx - ROFF(I);
        int i0 = base + 4*I, j0 = base + 4*J;
        int ra0=rowStart(i0+0)+c0, ra1=rowStart(i0+1)+c0,
            ra2=rowStart(i0+2)+c0, ra3=rowStart(i0+3)+c0;
        int rb0=rowStart(j0+0)+c0, rb1=rowStart(j0+1)+c0,
            rb2=rowStart(j0+2)+c0, rb3=rowStart(j0+3)+c0;
        float acc[4][4];
        #pragma unroll
        for (int ii=0;ii<4;++ii)
          #pragma unroll
          for (int jj=0;jj<4;++jj) acc[ii][jj]=0.f;
        #pragma unroll
        for (int q=0;q<4;++q){
          float4 A0=*(const float4*)&tri[ra0+4*q];
          float4 A1=*(const float4*)&tri[ra1+4*q];
          float4 A2=*(const float4*)&tri[ra2+4*q];
          float4 A3=*(const float4*)&tri[ra3+4*q];
          float4 B0=*(const float4*)&tri[rb0+4*q];
          float4 B1=*(const float4*)&tri[rb1+4*q];
          float4 B2=*(const float4*)&tri[rb2+4*q];
          float4 B3=*(const float4*)&tri[rb3+4*q];
          #define DOT4(Ai,Bj) (fmaf(Ai.x,Bj.x,fmaf(Ai.y,Bj.y,fmaf(Ai.z,Bj.z,Ai.w*Bj.w))))
          acc[0][0]+=DOT4(A0,B0); acc[0][1]+=DOT4(A0,B1); acc[0][2]+=DOT4(A0,B2); acc[0][3]+=DOT4(A0,B3);
          acc[1][0]+=DOT4(A1,B0); acc[1][1]+=DOT4(A1,B1); acc[1][2]+=DOT4(A1,B2); acc[1][3]+=DOT4(A1,B3);
          acc[2][0]+=DOT4(A2,B0); acc[2][1]+=DOT4(A2,B1); acc[2][2]+=DOT4(A2,B2); acc[2][3]+=DOT4(A2,B3);
          acc[3][0]+=DOT4(A3,B0); acc[3][1]+=DOT4(A3,B1); acc[3][2]+=DOT4(A3,B2); acc[3][3]+=DOT4(A3,B3);
          #undef DOT4
        }
        #pragma unroll
        for (int ii=0;ii<4;++ii){
          #pragma unroll
          for (int jj=0;jj<4;++jj){
            int gi=i0+ii, gj=j0+jj;
            if (gi>=gj) tri[rowStart(gi)+gj] -= acc[ii][jj];
          }
        }
      }
    }
    __syncthreads();
  }
}

// ---- wave-synchronous blocked Cholesky (64-thread workgroup, one batch) ----
__device__ void chol_factor_wave(float* tri, int lane){
  for (int kb=0; kb<8; ++kb){
    const int c0 = kb*16;
    chol_diag_gj(tri, c0, lane);
    __syncthreads();
    const int rem = 112 - c0;
    for (int rr=lane; rr<rem; rr+=64){       // panel: X = A * Linv^T
      const int r = c0+16+rr;
      const int rb = rowStart(r)+c0;
      float a[16];
      #pragma unroll
      for (int q=0;q<4;++q){
        float4 w = *(const float4*)&tri[rb+4*q];
        a[4*q+0]=w.x; a[4*q+1]=w.y; a[4*q+2]=w.z; a[4*q+3]=w.w;
      }
      float x[16];
      #pragma unroll
      for (int c=0;c<16;++c){
        float acc=0.f;
        const int lb = rowStart(c0+c)+c0;
        #pragma unroll
        for (int q=0;q<=(c>>2);++q){
          float4 w = *(const float4*)&tri[lb+4*q];
          if (4*q+0<=c) acc = fmaf(w.x, a[4*q+0], acc);
          if (4*q+1<=c) acc = fmaf(w.y, a[4*q+1], acc);
          if (4*q+2<=c) acc = fmaf(w.z, a[4*q+2], acc);
          if (4*q+3<=c) acc = fmaf(w.w, a[4*q+3], acc);
        }
        x[c]=acc;
      }
      #pragma unroll
      for (int q=0;q<4;++q){
        float4 w; w.x=x[4*q+0]; w.y=x[4*q+1]; w.z=x[4*q+2]; w.w=x[4*q+3];
        *(float4*)&tri[rb+4*q] = w;
      }
    }
    __syncthreads();
    if (rem > 0){                            // trailing update, 4x4 tiles
      const int base = c0+16;
      const int R = rem>>2;
      const int ntile = (R*(R+1))>>1;
      for (int idx=lane; idx<ntile; idx+=64){
        int I = rowOfIdx(idx);
        int J = idx - ROFF(I);
        int i0 = base + 4*I, j0 = base + 4*J;
        int ra0=rowStart(i0+0)+c0, ra1=rowStart(i0+1)+c0,
            ra2=rowStart(i0+2)+c0, ra3=rowStart(i0+3)+c0;
        int rb0=rowStart(j0+0)+c0, rb1=rowStart(j0+1)+c0,
            rb2=rowStart(j0+2)+c0, rb3=rowStart(j0+3)+c0;
        float acc[4][4];
        #pragma unroll
        for (int ii=0;ii<4;++ii)
          #pragma unroll
          for (int jj=0;jj<4;++jj) acc[ii][jj]=0.f;
        #pragma unroll
        for (int q=0;q<4;++q){
          float4 A0=*(const float4*)&tri[ra0+4*q];
          float4 A1=*(const float4*)&tri[ra1+4*q];
          float4 A2=*(const float4*)&tri[ra2+4*q];
          float4 A3=*(const float4*)&tri[ra3+4*q];
          float4 B0=*(const float4*)&tri[rb0+4*q];
          float4 B1=*(const float4*)&tri[rb1+4*q];
          float4 B2=*(const float4*)&tri[rb2+4*q];
          float4 B3=*(const float4*)&tri[rb3+4*q];
          #define DOT4(Ai,Bj) (fmaf(Ai.x,Bj.x,fmaf(Ai.y,Bj.y,fmaf(Ai.z,Bj.z,Ai.w*Bj.w))))
          acc[0][0]+=DOT4(A0,B0); acc[0][1]+=DOT4(A0,B1); acc[0][2]+=DOT4(A0,B2); acc[0][3]+=DOT4(A0,B3);
          acc[1][0]+=DOT4(A1,B0); acc[1][1]+=DOT4(A1,B1); acc[1][2]+=DOT4(A1,B2); acc[1][3]+=DOT4(A1,B3);
          acc[2][0]+=DOT4(A2,B0); acc[2][1]+=DOT4(A2,B1); acc[2][2]+=DOT4(A2,B2); acc[2][3]+=DOT4(A2,B3);
          acc[3][0]+=DOT4(A3,B0); acc[3][1]+=DOT4(A3,B1); acc[3][2]+=DOT4(A3,B2); acc[3][3]+=DOT4(A3,B3);
          #undef DOT4
        }
        #pragma unroll
        for (int ii=0;ii<4;++ii){
          #pragma unroll
          for (int jj=0;jj<4;++jj){
            int gi=i0+ii, gj=j0+jj;
            if (gi>=gj) tri[rowStart(gi)+gj] -= acc[ii][jj];
          }
        }
      }
    }
    __syncthreads();
  }
}

// wave-synchronous forward/backward solve; diag slots hold Linv
__device__ void tri_solve_wave(const float* tri, float* rhs, int lane){
  for (int kb=0;kb<8;++kb){
    const int c0=kb*16;
    {
      const int c = lane & 15;
      float v = (lane<16)? rhs[c0+c] : 0.f;
      float acc = 0.f;
      const int lb = rowStart(c0+c)+c0;
      #pragma unroll
      for (int cp=0;cp<16;++cp){
        float rcp = __shfl(v, cp, 64);
        if (cp<=c) acc = fmaf(tri[lb+cp], rcp, acc);
      }
      if (lane<16) rhs[c0+c] = acc;
    }
    __syncthreads();
    const int rem = 112-c0;
    for (int rr=lane; rr<rem; rr+=64){
      const int r = c0+16+rr;
      const int rb = rowStart(r)+c0;
      float acc = rhs[r];
      #pragma unroll
      for (int q=0;q<4;++q){
        float4 w = *(const float4*)&tri[rb+4*q];
        acc = fmaf(-w.x, rhs[c0+4*q+0], acc);
        acc = fmaf(-w.y, rhs[c0+4*q+1], acc);
        acc = fmaf(-w.z, rhs[c0+4*q+2], acc);
        acc = fmaf(-w.w, rhs[c0+4*q+3], acc);
      }
      rhs[r] = acc;
    }
    __syncthreads();
  }
  for (int kb=7;kb>=0;--kb){
    const int c0=kb*16;
    {
      const int c = lane & 15;
      float v = (lane<16)? rhs[c0+c] : 0.f;
      float acc = 0.f;
      #pragma unroll
      for (int cp=0;cp<16;++cp){
        float rcp = __shfl(v, cp, 64);
        if (cp>=c) acc = fmaf(tri[rowStart(c0+cp)+c0+c], rcp, acc);
      }
      if (lane<16) rhs[c0+c] = acc;
    }
    __syncthreads();
    for (int rr=lane; rr<c0; rr+=64){
      float acc = rhs[rr];
      #pragma unroll
      for (int c=0;c<16;++c) acc = fmaf(-tri[rowStart(c0+c)+rr], rhs[c0+c], acc);
      rhs[rr]=acc;
    }
    __syncthreads();
  }
}

// ---- precompute: chol(Q), then Qi = Q^{-1} and M1 = Qi G^T ----
__global__ __launch_bounds__(256) void k_prep(const float* __restrict__ Q,
        const float* __restrict__ Gm, float* __restrict__ Qi, float* __restrict__ M1)
{
  __shared__ __align__(16) float tri[TRI_SZ];
  __shared__ float Xl[128*32];
  const int t = threadIdx.x;
  const int lane = t&63, wid = t>>6;
  for (int idx=t; idx<8256; idx+=256){
    int i = rowOfIdx(idx); int j = idx - ROFF(i);
    tri[rowStart(i)+j] = Q[i*128+j];
  }
  __syncthreads();
  chol_factor(tri, t, lane, wid);
  for (int cc=0; cc<8; ++cc){
    const int a0 = (cc&3)*32;
    const bool ident = (cc<4);
    for (int idx=t; idx<4096; idx+=256){
      int i=idx>>5, j=idx&31;
      Xl[idx] = ident ? ((i==(a0+j))?1.f:0.f) : Gm[(a0+j)*128+i];
    }
    __syncthreads();
    for (int kb=0;kb<8;++kb){                    // forward: X := L^{-1} X
      const int c0=kb*16;
      if (t<32){
        float v[16], x[16];
        #pragma unroll
        for (int c=0;c<16;++c) v[c]=Xl[(c0+c)*32+t];
        #pragma unroll
        for (int c=0;c<16;++c){
          float acc=0.f;
          const int lb=rowStart(c0+c)+c0;
          #pragma unroll
          for (int cp=0;cp<16;++cp) if (cp<=c) acc=fmaf(tri[lb+cp], v[cp], acc);
          x[c]=acc;
        }
        #pragma unroll
        for (int c=0;c<16;++c) Xl[(c0+c)*32+t]=x[c];
      }
      __syncthreads();
      const int rem=112-c0;
      for (int rr=(t>>5); rr<rem; rr+=8){
        const int r=c0+16+rr, j=t&31;
        float acc=Xl[r*32+j];
        #pragma unroll
        for (int c=0;c<16;++c) acc = fmaf(-tri[rowStart(r)+c0+c], Xl[(c0+c)*32+j], acc);
        Xl[r*32+j]=acc;
      }
      __syncthreads();
    }
    for (int kb=7;kb>=0;--kb){                   // backward: X := L^{-T} X
      const int c0=kb*16;
      if (t<32){
        float v[16], x[16];
        #pragma unroll
        for (int c=0;c<16;++c) v[c]=Xl[(c0+c)*32+t];
        #pragma unroll
        for (int c=0;c<16;++c){
          float acc=0.f;
          #pragma unroll
          for (int cp=0;cp<16;++cp) if (cp>=c) acc=fmaf(tri[rowStart(c0+cp)+c0+c], v[cp], acc);
          x[c]=acc;
        }
        #pragma unroll
        for (int c=0;c<16;++c) Xl[(c0+c)*32+t]=x[c];
      }
      __syncthreads();
      for (int rr=(t>>5); rr<c0; rr+=8){
        const int j=t&31;
        float acc=Xl[rr*32+j];
        #pragma unroll
        for (int c=0;c<16;++c) acc = fmaf(-tri[rowStart(c0+c)+rr], Xl[(c0+c)*32+j], acc);
        Xl[rr*32+j]=acc;
      }
      __syncthreads();
    }
    float* dst = ident ? Qi : M1;
    for (int idx=t; idx<4096; idx+=256){
      int i=idx>>5, j=idx&31;
      dst[i*128+a0+j] = Xl[idx];
    }
    __syncthreads();
  }
}

// K = G * M1  (= G Qi G^T), plus its diagonal
__global__ __launch_bounds__(256) void k_kmat(const float* __restrict__ Gm,
        const float* __restrict__ M1, float* __restrict__ K, float* __restrict__ Kd){
  const int idx = blockIdx.x*256 + threadIdx.x;
  const int a = idx>>7, bcol = idx&127;
  float a0=0.f,a1=0.f,a2=0.f,a3=0.f;
  #pragma unroll
  for (int j=0;j<128;j+=4){
    a0 = fmaf(Gm[a*128+j+0], M1[(j+0)*128+bcol], a0);
    a1 = fmaf(Gm[a*128+j+1], M1[(j+1)*128+bcol], a1);
    a2 = fmaf(Gm[a*128+j+2], M1[(j+2)*128+bcol], a2);
    a3 = fmaf(Gm[a*128+j+3], M1[(j+3)*128+bcol], a3);
  }
  float acc = (a0+a1)+(a2+a3);
  K[idx] = acc;
  if (a==bcol) Kd[a]=acc;
}

// ---- init: state arrays + p transpose (n-major) ----
__global__ __launch_bounds__(256) void k_init(const float* __restrict__ p,
    float* __restrict__ Pt, float* __restrict__ S, float* __restrict__ LAM,
    float* __restrict__ GZ, float* __restrict__ QZ, float* __restrict__ Zst){
  int idx = blockIdx.x*256 + threadIdx.x;
  if (idx < 128*B_TOT){
    int i = idx/B_TOT, b = idx - i*B_TOT;
    Pt[idx] = p[b*128+i];
    S[idx]=1.f; LAM[idx]=1.f; GZ[idx]=0.f; QZ[idx]=0.f; Zst[idx]=0.f;
  }
}

// ---- k_B: stage1 + rhs = -(qz+p)+G^T wm ; tv = G Qi rhs (via M1^T) ----
__global__ __launch_bounds__(256) void k_B(const float* __restrict__ G,
    const float* __restrict__ M1, const float* __restrict__ Pt,
    const float* __restrict__ h,
    const float* __restrict__ S, const float* __restrict__ LAM,
    const float* __restrict__ GZ, const float* __restrict__ QZ,
    float* __restrict__ RHS, float* __restrict__ TV){
  __shared__ float wm_l[128*33];
  __shared__ float rhs_l[128*33];
  __shared__ float part_l[8*33];
  __shared__ float mu_l[TB];
  __shared__ float h_l[128];
  const int t=threadIdx.x, g=t>>5, bl=t&31;
  const int b = blockIdx.x*TB + bl;
  if (t<128) h_l[t]=h[t];
  __syncthreads();
  float sv[16], lv[16], rpv[16];
  float prod=0.f;
  #pragma unroll
  for (int q=0;q<16;++q){
    int i = g + 8*q;
    float s = S[i*B_TOT+b], l = LAM[i*B_TOT+b], gz = GZ[i*B_TOT+b];
    sv[q]=s; lv[q]=l; rpv[q]=gz+s-h_l[i];
    prod += s*l;
  }
  part_l[g*33+bl] = prod;
  __syncthreads();
  if (g==0){
    float m=0.f;
    #pragma unroll
    for (int q=0;q<8;++q) m += part_l[q*33+bl];
    mu_l[bl] = m*(1.f/128.f);
  }
  __syncthreads();
  const float mu = mu_l[bl];
  #pragma unroll
  for (int q=0;q<16;++q){
    int i=g+8*q;
    float rc = sv[q]*lv[q] - 0.1f*mu;
    wm_l[i*33+bl] = (rc - lv[q]*rpv[q])/sv[q] - lv[q];
  }
  __syncthreads();
  const int r0 = g*16;
  float acc[16];
  #pragma unroll
  for (int q=0;q<16;++q) acc[q] = -(QZ[(r0+q)*B_TOT+b] + Pt[(r0+q)*B_TOT+b]);
  #pragma unroll 2
  for (int j=0;j<128;++j){
    float wmv = wm_l[j*33+bl];
    const float4* gp = (const float4*)&G[j*128+r0];
    #pragma unroll
    for (int q4=0;q4<4;++q4){
      float4 gv = gp[q4];
      acc[4*q4+0]=fmaf(gv.x,wmv,acc[4*q4+0]);
      acc[4*q4+1]=fmaf(gv.y,wmv,acc[4*q4+1]);
      acc[4*q4+2]=fmaf(gv.z,wmv,acc[4*q4+2]);
      acc[4*q4+3]=fmaf(gv.w,wmv,acc[4*q4+3]);
    }
  }
  #pragma unroll
  for (int q=0;q<16;++q){
    rhs_l[(r0+q)*33+bl]=acc[q];
    RHS[(r0+q)*B_TOT+b]=acc[q];
  }
  __syncthreads();
  #pragma unroll
  for (int q=0;q<16;++q) acc[q]=0.f;
  #pragma unroll 2
  for (int j=0;j<128;++j){
    float rv = rhs_l[j*33+bl];
    const float4* mp = (const float4*)&M1[j*128+r0];
    #pragma unroll
    for (int q4=0;q4<4;++q4){
      float4 mv = mp[q4];
      acc[4*q4+0]=fmaf(mv.x,rv,acc[4*q4+0]);
      acc[4*q4+1]=fmaf(mv.y,rv,acc[4*q4+1]);
      acc[4*q4+2]=fmaf(mv.z,rv,acc[4*q4+2]);
      acc[4*q4+3]=fmaf(mv.w,rv,acc[4*q4+3]);
    }
  }
  #pragma unroll
  for (int q=0;q<16;++q) TV[(r0+q)*B_TOT+b]=acc[q];
}

// ---- k_C: one wave per batch: build S(Dinv+K)S, Cholesky, solve, step ----
__global__ __launch_bounds__(64) void k_C(const float* __restrict__ K,
    const float* __restrict__ Kd, const float* __restrict__ h,
    const float* __restrict__ TV,
    float* __restrict__ S, float* __restrict__ LAM, float* __restrict__ GZ,
    float* __restrict__ Y, float* __restrict__ ALPHA){
  __shared__ __align__(16) float tri[TRI_SZ];
  __shared__ float scl_l[128];
  __shared__ float sh_t[128];
  const int lane = threadIdx.x, b = blockIdx.x;
  const int i0 = lane, i1 = lane+64;
  float s0=S[i0*B_TOT+b], l0=LAM[i0*B_TOT+b], g0=GZ[i0*B_TOT+b];
  float s1=S[i1*B_TOT+b], l1=LAM[i1*B_TOT+b], g1=GZ[i1*B_TOT+b];
  float rp0 = g0+s0-h[i0], rp1 = g1+s1-h[i1];
  float prod = s0*l0 + s1*l1;
  #pragma unroll
  for (int o=32;o>0;o>>=1) prod += __shfl_xor(prod,o,64);
  const float mu = prod*(1.f/128.f);
  float rc0 = s0*l0 - 0.1f*mu,      rc1 = s1*l1 - 0.1f*mu;
  float di0 = fminf(s0/l0,1e30f),   di1 = fminf(s1/l1,1e30f);
  float sc0 = rsqrtf(Kd[i0]+di0),   sc1 = rsqrtf(Kd[i1]+di1);
  scl_l[i0]=sc0; scl_l[i1]=sc1;
  sh_t[i0]=TV[i0*B_TOT+b]*sc0; sh_t[i1]=TV[i1*B_TOT+b]*sc1;
  __syncthreads();
  // build equilibrated triangle (unit diag), row sweep, coalesced K reads
  #pragma unroll 4
  for (int i=0;i<64;++i){
    if (lane<=i)
      tri[rowStart(i)+lane] = (lane==i)?1.f : K[i*128+lane]*scl_l[i]*sc0;
  }
  #pragma unroll 4
  for (int i=64;i<128;++i){
    float sci = scl_l[i];
    tri[rowStart(i)+lane] = K[i*128+lane]*sci*sc0;   // lane<64<=i: never diag
    int j2 = lane+64;
    if (j2<=i) tri[rowStart(i)+j2] = (j2==i)?1.f : K[i*128+j2]*sci*sc1;
  }
  __syncthreads();
  chol_factor_wave(tri, lane);
  tri_solve_wave(tri, sh_t, lane);
  float y0 = sh_t[i0]*sc0, y1 = sh_t[i1]*sc1;
  float gd0 = di0*y0,      gd1 = di1*y1;   // G dz = Dinv .* y (Woodbury identity)
  float ds0 = -rp0-gd0,    ds1 = -rp1-gd1;
  float dl0 = (-rc0-l0*ds0)/s0, dl1 = (-rc1-l1*ds1)/s1;
  float ra = 1e9f;
  if (ds0<0.f) ra = -s0/ds0;
  if (dl0<0.f) ra = fminf(ra,-l0/dl0);
  if (ds1<0.f) ra = fminf(ra,-s1/ds1);
  if (dl1<0.f) ra = fminf(ra,-l1/dl1);
  #pragma unroll
  for (int o=32;o>0;o>>=1) ra = fminf(ra,__shfl_xor(ra,o,64));
  const float alpha = fminf(1.0f, 0.99f*ra);
  S[i0*B_TOT+b]=s0+alpha*ds0;   S[i1*B_TOT+b]=s1+alpha*ds1;
  LAM[i0*B_TOT+b]=l0+alpha*dl0; LAM[i1*B_TOT+b]=l1+alpha*dl1;
  GZ[i0*B_TOT+b]=g0+alpha*gd0;  GZ[i1*B_TOT+b]=g1+alpha*gd1;
  Y[i0*B_TOT+b]=y0;             Y[i1*B_TOT+b]=y1;
  if (lane==0) ALPHA[b]=alpha;
}

// ---- k_D: v = rhs - G^T y ; dz = Qi v ; z += a dz ; qz += a v ----
__global__ __launch_bounds__(256) void k_D(const float* __restrict__ G,
    const float* __restrict__ Qi, const float* __restrict__ RHS,
    const float* __restrict__ Y, const float* __restrict__ ALPHA,
    float* __restrict__ Zst, float* __restrict__ QZ){
  __shared__ float y_l[128*33];
  __shared__ float v_l[128*33];
  const int t=threadIdx.x, g=t>>5, bl=t&31;
  const int b = blockIdx.x*TB + bl;
  #pragma unroll
  for (int q=0;q<16;++q){
    int i=g+8*q;
    y_l[i*33+bl] = Y[i*B_TOT+b];
  }
  const float alpha = ALPHA[b];
  __syncthreads();
  const int r0=g*16;
  float acc[16];
  #pragma unroll
  for (int q=0;q<16;++q) acc[q]=RHS[(r0+q)*B_TOT+b];
  #pragma unroll 2
  for (int j=0;j<128;++j){
    float yv = y_l[j*33+bl];
    const float4* gp=(const float4*)&G[j*128+r0];
    #pragma unroll
    for (int q4=0;q4<4;++q4){
      float4 gv=gp[q4];
      acc[4*q4+0]=fmaf(-gv.x,yv,acc[4*q4+0]);
      acc[4*q4+1]=fmaf(-gv.y,yv,acc[4*q4+1]);
      acc[4*q4+2]=fmaf(-gv.z,yv,acc[4*q4+2]);
      acc[4*q4+3]=fmaf(-gv.w,yv,acc[4*q4+3]);
    }
  }
  #pragma unroll
  for (int q=0;q<16;++q){
    v_l[(r0+q)*33+bl]=acc[q];
    float* qp=&QZ[(r0+q)*B_TOT+b];
    *qp = *qp + alpha*acc[q];            // qz += a*v  (Q dz == v)
  }
  __syncthreads();
  #pragma unroll
  for (int q=0;q<16;++q) acc[q]=0.f;
  #pragma unroll 2
  for (int j=0;j<128;++j){
    float vv = v_l[j*33+bl];
    const float4* qp4=(const float4*)&Qi[j*128+r0];
    #pragma unroll
    for (int q4=0;q4<4;++q4){
      float4 qv=qp4[q4];
      acc[4*q4+0]=fmaf(qv.x,vv,acc[4*q4+0]);
      acc[4*q4+1]=fmaf(qv.y,vv,acc[4*q4+1]);
      acc[4*q4+2]=fmaf(qv.z,vv,acc[4*q4+2]);
      acc[4*q4+3]=fmaf(qv.w,vv,acc[4*q4+3]);
    }
  }
  #pragma unroll
  for (int q=0;q<16;++q){
    float* zp=&Zst[(r0+q)*B_TOT+b];
    *zp = *zp + alpha*acc[q];            // z += a*dz
  }
}

// out = log_softmax(Z.reshape(10, 32768), axis=1), Z stored n-major [i][B]
__global__ __launch_bounds__(1024) void k_logsoftmax(const float* __restrict__ Zst,
                                                     float* __restrict__ out){
  __shared__ float red[16];
  __shared__ float sval[2];
  const int r = blockIdx.x, t = threadIdx.x;
  float m = -1e30f;
  for (int k=t;k<32768;k+=1024){
    float v = Zst[(k&127)*B_TOT + r*256 + (k>>7)];
    m = fmaxf(m, v);
  }
  #pragma unroll
  for (int o=32;o>0;o>>=1) m = fmaxf(m, __shfl_down(m,o,64));
  if ((t&63)==0) red[t>>6] = m;
  __syncthreads();
  if (t==0){ float mm=red[0]; for (int w=1;w<16;++w) mm=fmaxf(mm,red[w]); sval[0]=mm; }
  __syncthreads();
  const float mx = sval[0];
  float s=0.f;
  for (int k=t;k<32768;k+=1024){
    float v = Zst[(k&127)*B_TOT + r*256 + (k>>7)];
    s += expf(v-mx);
  }
  #pragma unroll
  for (int o=32;o>0;o>>=1) s += __shfl_down(s,o,64);
  if ((t&63)==0) red[t>>6]=s;
  __syncthreads();
  if (t==0){ float ss=0.f; for (int w=0;w<16;++w) ss+=red[w]; sval[1]=logf(ss); }
  __syncthreads();
  const float lse = sval[1];
  for (int k=t;k<32768;k+=1024){
    float v = Zst[(k&127)*B_TOT + r*256 + (k>>7)];
    out[(size_t)r*32768+k] = v-mx-lse;
  }
}

extern "C" void kernel_launch(void* const* d_in, const int* in_sizes, int n_in,
                              void* d_out, int out_size, void* d_ws, size_t ws_size,
                              hipStream_t stream){
  // inputs: 0=x (unused), 1=Q[128x128], 2=p[2560x128], 3=G[128x128], 4=h[128], 5=m
  const float* Q = (const float*)d_in[1];
  const float* p = (const float*)d_in[2];
  const float* G = (const float*)d_in[3];
  const float* h = (const float*)d_in[4];
  float* ws  = (float*)d_ws;
  const int NE = 128*B_TOT;              // 327680
  float* Zst = ws;                       // [128][2560]
  float* Qi  = Zst + NE;                 // 16384
  float* M1  = Qi + 16384;               // 16384
  float* K   = M1 + 16384;               // 16384
  float* Kd  = K + 16384;                // 128
  float* ALPHA = Kd + 128;               // 2560
  float* Pt  = ALPHA + 2560;             // NE
  float* S   = Pt + NE;                  // NE
  float* LAM = S + NE;                   // NE
  float* GZ  = LAM + NE;                 // NE
  float* QZ  = GZ + NE;                  // NE
  float* RHS = QZ + NE;                  // NE
  float* TV  = RHS + NE;                 // NE
  float* Y   = TV + NE;                  // NE
  float* out = (float*)d_out;

  hipLaunchKernelGGL(k_prep, dim3(1), dim3(256), 0, stream, Q, G, Qi, M1);
  hipLaunchKernelGGL(k_kmat, dim3(64), dim3(256), 0, stream, G, M1, K, Kd);
  hipLaunchKernelGGL(k_init, dim3((NE+255)/256), dim3(256), 0, stream,
                     p, Pt, S, LAM, GZ, QZ, Zst);
  for (int it=0; it<20; ++it){
    hipLaunchKernelGGL(k_B, dim3(NB), dim3(256), 0, stream,
                       G, M1, Pt, h, S, LAM, GZ, QZ, RHS, TV);
    hipLaunchKernelGGL(k_C, dim3(B_TOT), dim3(64), 0, stream,
                       K, Kd, h, TV, S, LAM, GZ, Y, ALPHA);
    hipLaunchKernelGGL(k_D, dim3(NB), dim3(256), 0, stream,
                       G, Qi, RHS, Y, ALPHA, Zst, QZ);
  }
  hipLaunchKernelGGL(k_logsoftmax, dim3(10), dim3(1024), 0, stream, Zst, out);
}

// Round 7
// 8739.061 us; speedup vs baseline: 3.8242x; 1.1983x over previous
//
#include <hip/hip_runtime.h>
#include <math.h>

// OptNet IPM QP solve via Woodbury, Round 7: 2 waves/SIMD for k_C.
//  M = Q + G^T D G;  M^{-1} = Qi - Qi G^T (Dinv + K)^{-1} G Qi,  K = G Qi G^T
// Round-6 counters: k_C wall 436K cyc/batch vs 92K VALU -> ~344K LDS-latency
// stall cycles with 1 wave/SIMD (64t blocks, LDS-capped 4 blocks/CU). Round 7:
// k_C uses 128-thread blocks (4 blocks/CU = 8 waves = 2/SIMD) so a co-resident
// block's wave hides the other's LDS latency; tri-solve diag steps rewritten as
// parallel LDS dot-products (no shuffle chains); GJ drops the Newton step.

#define B_TOT 2560
#define TB 32
#define NB (B_TOT/TB)

__device__ __forceinline__ int ROFF(int i){ return (i*(i+1))>>1; }
// padded-row packed lower triangle: row i starts at rowStart(i), 16B aligned
__device__ __forceinline__ int rowStart(int i){
  int a=i>>2, b=i&3;
  return ((a+1)*((a<<1)+b))<<2;
}
#define TRI_SZ 8448

__device__ __forceinline__ int rowOfIdx(int idx){
  int i = (int)((sqrtf(8.f*(float)idx+1.f)-1.f)*0.5f);
  while (((i+1)*(i+2)>>1) <= idx) ++i;
  while (((i*(i+1))>>1) > idx) --i;
  return i;
}

// ---- Gauss-Jordan 16x16 diag block: factor AND invert (lanes 0..15 of one wave) ----
__device__ __forceinline__ void chol_diag_gj(float* tri, int c0, int lane){
  float rowA[16], rowW[16];
  const int r = lane;
  #pragma unroll
  for (int j=0;j<16;++j){ rowA[j]=0.f; rowW[j]=0.f; }
  if (r < 16){
    const float* src = &tri[rowStart(c0+r)+c0];
    #pragma unroll
    for (int q=0;q<4;++q){
      if (q <= (r>>2)){
        float4 w = *(const float4*)&src[4*q];
        rowA[4*q+0]=w.x; rowA[4*q+1]=w.y; rowA[4*q+2]=w.z; rowA[4*q+3]=w.w;
      }
    }
    #pragma unroll
    for (int j=0;j<16;++j) if (j>r) rowA[j]=0.f;
    #pragma unroll
    for (int j=0;j<16;++j) rowW[j] = (j==r)?1.f:0.f;
  }
  #pragma unroll
  for (int k=0;k<16;++k){
    float akk = __shfl(rowA[k], k, 64);
    akk = fmaxf(akk, 1e-12f);
    float linv = rsqrtf(akk);                  // v_rsq: ~1-2 ulp, good enough
    float lrk = rowA[k]*linv;                  // valid for r>=k
    if (r==k){
      #pragma unroll
      for (int c=0;c<16;++c) rowW[c] *= linv;  // final Linv row k
    }
    #pragma unroll
    for (int j=k+1;j<16;++j){
      float ljk = __shfl(lrk, j, 64);
      if (r>=j) rowA[j] = fmaf(-lrk, ljk, rowA[j]);
    }
    #pragma unroll
    for (int c=0;c<=k;++c){
      float wkc = __shfl(rowW[c], k, 64);
      if (r>k) rowW[c] = fmaf(-lrk, wkc, rowW[c]);
    }
  }
  if (r < 16){
    float* dst = &tri[rowStart(c0+r)+c0];
    #pragma unroll
    for (int q=0;q<4;++q){
      if (q <= (r>>2)){
        float4 w; w.x=rowW[4*q+0]; w.y=rowW[4*q+1]; w.z=rowW[4*q+2]; w.w=rowW[4*q+3];
        *(float4*)&dst[4*q] = w;
      }
    }
  }
}

// ---- 256-thread blocked Cholesky (used by k_prep only) ----
__device__ void chol_factor(float* tri, int t, int lane, int wid){
  for (int kb=0; kb<8; ++kb){
    const int c0 = kb*16;
    if (wid==(kb&3)) chol_diag_gj(tri, c0, lane);
    __syncthreads();
    const int rem = 112 - c0;
    if (t < rem){
      const int r = c0+16+t;
      const int rb = rowStart(r)+c0;
      float a[16];
      #pragma unroll
      for (int q=0;q<4;++q){
        float4 w = *(const float4*)&tri[rb+4*q];
        a[4*q+0]=w.x; a[4*q+1]=w.y; a[4*q+2]=w.z; a[4*q+3]=w.w;
      }
      float x[16];
      #pragma unroll
      for (int c=0;c<16;++c){
        float acc=0.f;
        const int lb = rowStart(c0+c)+c0;
        #pragma unroll
        for (int q=0;q<=(c>>2);++q){
          float4 w = *(const float4*)&tri[lb+4*q];
          if (4*q+0<=c) acc = fmaf(w.x, a[4*q+0], acc);
          if (4*q+1<=c) acc = fmaf(w.y, a[4*q+1], acc);
          if (4*q+2<=c) acc = fmaf(w.z, a[4*q+2], acc);
          if (4*q+3<=c) acc = fmaf(w.w, a[4*q+3], acc);
        }
        x[c]=acc;
      }
      #pragma unroll
      for (int q=0;q<4;++q){
        float4 w; w.x=x[4*q+0]; w.y=x[4*q+1]; w.z=x[4*q+2]; w.w=x[4*q+3];
        *(float4*)&tri[rb+4*q] = w;
      }
    }
    __syncthreads();
    if (rem > 0){
      const int base = c0+16;
      const int R = rem>>2;
      const int ntile = (R*(R+1))>>1;
      for (int idx=t; idx<ntile; idx+=256){
        int I = rowOfIdx(idx);
        int J = idx - ROFF(I);
        int i0 = base + 4*I, j0 = base + 4*J;
        int ra0=rowStart(i0+0)+c0, ra1=rowStart(i0+1)+c0,
            ra2=rowStart(i0+2)+c0, ra3=rowStart(i0+3)+c0;
        int rb0=rowStart(j0+0)+c0, rb1=rowStart(j0+1)+c0,
            rb2=rowStart(j0+2)+c0, rb3=rowStart(j0+3)+c0;
        float acc[4][4];
        #pragma unroll
        for (int ii=0;ii<4;++ii)
          #pragma unroll
          for (int jj=0;jj<4;++jj) acc[ii][jj]=0.f;
        #pragma unroll
        for (int q=0;q<4;++q){
          float4 A0=*(const float4*)&tri[ra0+4*q];
          float4 A1=*(const float4*)&tri[ra1+4*q];
          float4 A2=*(const float4*)&tri[ra2+4*q];
          float4 A3=*(const float4*)&tri[ra3+4*q];
          float4 B0=*(const float4*)&tri[rb0+4*q];
          float4 B1=*(const float4*)&tri[rb1+4*q];
          float4 B2=*(const float4*)&tri[rb2+4*q];
          float4 B3=*(const float4*)&tri[rb3+4*q];
          #define DOT4(Ai,Bj) (fmaf(Ai.x,Bj.x,fmaf(Ai.y,Bj.y,fmaf(Ai.z,Bj.z,Ai.w*Bj.w))))
          acc[0][0]+=DOT4(A0,B0); acc[0][1]+=DOT4(A0,B1); acc[0][2]+=DOT4(A0,B2); acc[0][3]+=DOT4(A0,B3);
          acc[1][0]+=DOT4(A1,B0); acc[1][1]+=DOT4(A1,B1); acc[1][2]+=DOT4(A1,B2); acc[1][3]+=DOT4(A1,B3);
          acc[2][0]+=DOT4(A2,B0); acc[2][1]+=DOT4(A2,B1); acc[2][2]+=DOT4(A2,B2); acc[2][3]+=DOT4(A2,B3);
          acc[3][0]+=DOT4(A3,B0); acc[3][1]+=DOT4(A3,B1); acc[3][2]+=DOT4(A3,B2); acc[3][3]+=DOT4(A3,B3);
          #undef DOT4
        }
        #pragma unroll
        for (int ii=0;ii<4;++ii){
          #pragma unroll
          for (int jj=0;jj<4;++jj){
            int gi=i0+ii, gj=j0+jj;
            if (gi>=gj) tri[rowStart(gi)+gj] -= acc[ii][jj];
          }
        }
      }
    }
    __syncthreads();
  }
}

// ---- 128-thread blocked Cholesky (k_C): GJ on wave0, panel/trailing on both ----
__device__ void chol_factor_w2(float* tri, int t, int lane, int wid){
  for (int kb=0; kb<8; ++kb){
    const int c0 = kb*16;
    if (wid==0) chol_diag_gj(tri, c0, lane);
    __syncthreads();
    const int rem = 112 - c0;
    if (t < rem){                        // panel: X = A * Linv^T (single pass)
      const int r = c0+16+t;
      const int rb = rowStart(r)+c0;
      float a[16];
      #pragma unroll
      for (int q=0;q<4;++q){
        float4 w = *(const float4*)&tri[rb+4*q];
        a[4*q+0]=w.x; a[4*q+1]=w.y; a[4*q+2]=w.z; a[4*q+3]=w.w;
      }
      float x[16];
      #pragma unroll
      for (int c=0;c<16;++c){
        float acc=0.f;
        const int lb = rowStart(c0+c)+c0;
        #pragma unroll
        for (int q=0;q<=(c>>2);++q){
          float4 w = *(const float4*)&tri[lb+4*q];
          if (4*q+0<=c) acc = fmaf(w.x, a[4*q+0], acc);
          if (4*q+1<=c) acc = fmaf(w.y, a[4*q+1], acc);
          if (4*q+2<=c) acc = fmaf(w.z, a[4*q+2], acc);
          if (4*q+3<=c) acc = fmaf(w.w, a[4*q+3], acc);
        }
        x[c]=acc;
      }
      #pragma unroll
      for (int q=0;q<4;++q){
        float4 w; w.x=x[4*q+0]; w.y=x[4*q+1]; w.z=x[4*q+2]; w.w=x[4*q+3];
        *(float4*)&tri[rb+4*q] = w;
      }
    }
    __syncthreads();
    if (rem > 0){                        // trailing update, 4x4 tiles over 128 thr
      const int base = c0+16;
      const int R = rem>>2;
      const int ntile = (R*(R+1))>>1;
      for (int idx=t; idx<ntile; idx+=128){
        int I = rowOfIdx(idx);
        int J = idx - ROFF(I);
        int i0 = base + 4*I, j0 = base + 4*J;
        int ra0=rowStart(i0+0)+c0, ra1=rowStart(i0+1)+c0,
            ra2=rowStart(i0+2)+c0, ra3=rowStart(i0+3)+c0;
        int rb0=rowStart(j0+0)+c0, rb1=rowStart(j0+1)+c0,
            rb2=rowStart(j0+2)+c0, rb3=rowStart(j0+3)+c0;
        float acc[4][4];
        #pragma unroll
        for (int ii=0;ii<4;++ii)
          #pragma unroll
          for (int jj=0;jj<4;++jj) acc[ii][jj]=0.f;
        #pragma unroll
        for (int q=0;q<4;++q){
          float4 A0=*(const float4*)&tri[ra0+4*q];
          float4 A1=*(const float4*)&tri[ra1+4*q];
          float4 A2=*(const float4*)&tri[ra2+4*q];
          float4 A3=*(const float4*)&tri[ra3+4*q];
          float4 B0=*(const float4*)&tri[rb0+4*q];
          float4 B1=*(const float4*)&tri[rb1+4*q];
          float4 B2=*(const float4*)&tri[rb2+4*q];
          float4 B3=*(const float4*)&tri[rb3+4*q];
          #define DOT4(Ai,Bj) (fmaf(Ai.x,Bj.x,fmaf(Ai.y,Bj.y,fmaf(Ai.z,Bj.z,Ai.w*Bj.w))))
          acc[0][0]+=DOT4(A0,B0); acc[0][1]+=DOT4(A0,B1); acc[0][2]+=DOT4(A0,B2); acc[0][3]+=DOT4(A0,B3);
          acc[1][0]+=DOT4(A1,B0); acc[1][1]+=DOT4(A1,B1); acc[1][2]+=DOT4(A1,B2); acc[1][3]+=DOT4(A1,B3);
          acc[2][0]+=DOT4(A2,B0); acc[2][1]+=DOT4(A2,B1); acc[2][2]+=DOT4(A2,B2); acc[2][3]+=DOT4(A2,B3);
          acc[3][0]+=DOT4(A3,B0); acc[3][1]+=DOT4(A3,B1); acc[3][2]+=DOT4(A3,B2); acc[3][3]+=DOT4(A3,B3);
          #undef DOT4
        }
        #pragma unroll
        for (int ii=0;ii<4;++ii){
          #pragma unroll
          for (int jj=0;jj<4;++jj){
            int gi=i0+ii, gj=j0+jj;
            if (gi>=gj) tri[rowStart(gi)+gj] -= acc[ii][jj];
          }
        }
      }
    }
    __syncthreads();
  }
}

// 128-thread forward/backward solve; diag slots hold Linv; rhs in LDS.
// Diag steps = parallel LDS dot products (no shuffle chains).
__device__ void tri_solve_w2(const float* tri, float* rhs, int t){
  for (int kb=0;kb<8;++kb){
    const int c0=kb*16;
    if (t<16){                            // y_blk = Linv * r_blk
      const int c=t;
      const float* lrow = &tri[rowStart(c0+c)+c0];
      float acc=0.f;
      #pragma unroll
      for (int cp=0;cp<16;++cp) if (cp<=c) acc = fmaf(lrow[cp], rhs[c0+cp], acc);
      rhs[c0+c] = acc;                    // wave-lockstep: all reads precede store
    }
    __syncthreads();
    const int rem = 112-c0;
    if (t<rem){
      const int r = c0+16+t;
      const int rb = rowStart(r)+c0;
      float acc = rhs[r];
      #pragma unroll
      for (int q=0;q<4;++q){
        float4 w = *(const float4*)&tri[rb+4*q];
        acc = fmaf(-w.x, rhs[c0+4*q+0], acc);
        acc = fmaf(-w.y, rhs[c0+4*q+1], acc);
        acc = fmaf(-w.z, rhs[c0+4*q+2], acc);
        acc = fmaf(-w.w, rhs[c0+4*q+3], acc);
      }
      rhs[r] = acc;
    }
    __syncthreads();
  }
  for (int kb=7;kb>=0;--kb){
    const int c0=kb*16;
    if (t<16){                            // x_blk = Linv^T * r_blk
      const int c=t;
      float acc=0.f;
      #pragma unroll
      for (int cp=0;cp<16;++cp)
        if (cp>=c) acc = fmaf(tri[rowStart(c0+cp)+c0+c], rhs[c0+cp], acc);
      rhs[c0+c] = acc;
    }
    __syncthreads();
    if (t<c0){
      float acc = rhs[t];
      #pragma unroll
      for (int c=0;c<16;++c) acc = fmaf(-tri[rowStart(c0+c)+t], rhs[c0+c], acc);
      rhs[t]=acc;
    }
    __syncthreads();
  }
}

// ---- precompute: chol(Q), then Qi = Q^{-1} and M1 = Qi G^T ----
__global__ __launch_bounds__(256) void k_prep(const float* __restrict__ Q,
        const float* __restrict__ Gm, float* __restrict__ Qi, float* __restrict__ M1)
{
  __shared__ __align__(16) float tri[TRI_SZ];
  __shared__ float Xl[128*32];
  const int t = threadIdx.x;
  const int lane = t&63, wid = t>>6;
  for (int idx=t; idx<8256; idx+=256){
    int i = rowOfIdx(idx); int j = idx - ROFF(i);
    tri[rowStart(i)+j] = Q[i*128+j];
  }
  __syncthreads();
  chol_factor(tri, t, lane, wid);
  for (int cc=0; cc<8; ++cc){
    const int a0 = (cc&3)*32;
    const bool ident = (cc<4);
    for (int idx=t; idx<4096; idx+=256){
      int i=idx>>5, j=idx&31;
      Xl[idx] = ident ? ((i==(a0+j))?1.f:0.f) : Gm[(a0+j)*128+i];
    }
    __syncthreads();
    for (int kb=0;kb<8;++kb){                    // forward: X := L^{-1} X
      const int c0=kb*16;
      if (t<32){
        float v[16], x[16];
        #pragma unroll
        for (int c=0;c<16;++c) v[c]=Xl[(c0+c)*32+t];
        #pragma unroll
        for (int c=0;c<16;++c){
          float acc=0.f;
          const int lb=rowStart(c0+c)+c0;
          #pragma unroll
          for (int cp=0;cp<16;++cp) if (cp<=c) acc=fmaf(tri[lb+cp], v[cp], acc);
          x[c]=acc;
        }
        #pragma unroll
        for (int c=0;c<16;++c) Xl[(c0+c)*32+t]=x[c];
      }
      __syncthreads();
      const int rem=112-c0;
      for (int rr=(t>>5); rr<rem; rr+=8){
        const int r=c0+16+rr, j=t&31;
        float acc=Xl[r*32+j];
        #pragma unroll
        for (int c=0;c<16;++c) acc = fmaf(-tri[rowStart(r)+c0+c], Xl[(c0+c)*32+j], acc);
        Xl[r*32+j]=acc;
      }
      __syncthreads();
    }
    for (int kb=7;kb>=0;--kb){                   // backward: X := L^{-T} X
      const int c0=kb*16;
      if (t<32){
        float v[16], x[16];
        #pragma unroll
        for (int c=0;c<16;++c) v[c]=Xl[(c0+c)*32+t];
        #pragma unroll
        for (int c=0;c<16;++c){
          float acc=0.f;
          #pragma unroll
          for (int cp=0;cp<16;++cp) if (cp>=c) acc=fmaf(tri[rowStart(c0+cp)+c0+c], v[cp], acc);
          x[c]=acc;
        }
        #pragma unroll
        for (int c=0;c<16;++c) Xl[(c0+c)*32+t]=x[c];
      }
      __syncthreads();
      for (int rr=(t>>5); rr<c0; rr+=8){
        const int j=t&31;
        float acc=Xl[rr*32+j];
        #pragma unroll
        for (int c=0;c<16;++c) acc = fmaf(-tri[rowStart(c0+c)+rr], Xl[(c0+c)*32+j], acc);
        Xl[rr*32+j]=acc;
      }
      __syncthreads();
    }
    float* dst = ident ? Qi : M1;
    for (int idx=t; idx<4096; idx+=256){
      int i=idx>>5, j=idx&31;
      dst[i*128+a0+j] = Xl[idx];
    }
    __syncthreads();
  }
}

// K = G * M1  (= G Qi G^T), plus its diagonal
__global__ __launch_bounds__(256) void k_kmat(const float* __restrict__ Gm,
        const float* __restrict__ M1, float* __restrict__ K, float* __restrict__ Kd){
  const int idx = blockIdx.x*256 + threadIdx.x;
  const int a = idx>>7, bcol = idx&127;
  float a0=0.f,a1=0.f,a2=0.f,a3=0.f;
  #pragma unroll
  for (int j=0;j<128;j+=4){
    a0 = fmaf(Gm[a*128+j+0], M1[(j+0)*128+bcol], a0);
    a1 = fmaf(Gm[a*128+j+1], M1[(j+1)*128+bcol], a1);
    a2 = fmaf(Gm[a*128+j+2], M1[(j+2)*128+bcol], a2);
    a3 = fmaf(Gm[a*128+j+3], M1[(j+3)*128+bcol], a3);
  }
  float acc = (a0+a1)+(a2+a3);
  K[idx] = acc;
  if (a==bcol) Kd[a]=acc;
}

// ---- init: state arrays + p transpose (n-major) ----
__global__ __launch_bounds__(256) void k_init(const float* __restrict__ p,
    float* __restrict__ Pt, float* __restrict__ S, float* __restrict__ LAM,
    float* __restrict__ GZ, float* __restrict__ QZ, float* __restrict__ Zst){
  int idx = blockIdx.x*256 + threadIdx.x;
  if (idx < 128*B_TOT){
    int i = idx/B_TOT, b = idx - i*B_TOT;
    Pt[idx] = p[b*128+i];
    S[idx]=1.f; LAM[idx]=1.f; GZ[idx]=0.f; QZ[idx]=0.f; Zst[idx]=0.f;
  }
}

// ---- k_B: stage1 + rhs = -(qz+p)+G^T wm ; tv = G Qi rhs (via M1^T) ----
__global__ __launch_bounds__(256) void k_B(const float* __restrict__ G,
    const float* __restrict__ M1, const float* __restrict__ Pt,
    const float* __restrict__ h,
    const float* __restrict__ S, const float* __restrict__ LAM,
    const float* __restrict__ GZ, const float* __restrict__ QZ,
    float* __restrict__ RHS, float* __restrict__ TV){
  __shared__ float wm_l[128*33];
  __shared__ float rhs_l[128*33];
  __shared__ float part_l[8*33];
  __shared__ float mu_l[TB];
  __shared__ float h_l[128];
  const int t=threadIdx.x, g=t>>5, bl=t&31;
  const int b = blockIdx.x*TB + bl;
  if (t<128) h_l[t]=h[t];
  __syncthreads();
  float sv[16], lv[16], rpv[16];
  float prod=0.f;
  #pragma unroll
  for (int q=0;q<16;++q){
    int i = g + 8*q;
    float s = S[i*B_TOT+b], l = LAM[i*B_TOT+b], gz = GZ[i*B_TOT+b];
    sv[q]=s; lv[q]=l; rpv[q]=gz+s-h_l[i];
    prod += s*l;
  }
  part_l[g*33+bl] = prod;
  __syncthreads();
  if (g==0){
    float m=0.f;
    #pragma unroll
    for (int q=0;q<8;++q) m += part_l[q*33+bl];
    mu_l[bl] = m*(1.f/128.f);
  }
  __syncthreads();
  const float mu = mu_l[bl];
  #pragma unroll
  for (int q=0;q<16;++q){
    int i=g+8*q;
    float rc = sv[q]*lv[q] - 0.1f*mu;
    wm_l[i*33+bl] = (rc - lv[q]*rpv[q])/sv[q] - lv[q];
  }
  __syncthreads();
  const int r0 = g*16;
  float acc[16];
  #pragma unroll
  for (int q=0;q<16;++q) acc[q] = -(QZ[(r0+q)*B_TOT+b] + Pt[(r0+q)*B_TOT+b]);
  #pragma unroll 2
  for (int j=0;j<128;++j){
    float wmv = wm_l[j*33+bl];
    const float4* gp = (const float4*)&G[j*128+r0];
    #pragma unroll
    for (int q4=0;q4<4;++q4){
      float4 gv = gp[q4];
      acc[4*q4+0]=fmaf(gv.x,wmv,acc[4*q4+0]);
      acc[4*q4+1]=fmaf(gv.y,wmv,acc[4*q4+1]);
      acc[4*q4+2]=fmaf(gv.z,wmv,acc[4*q4+2]);
      acc[4*q4+3]=fmaf(gv.w,wmv,acc[4*q4+3]);
    }
  }
  #pragma unroll
  for (int q=0;q<16;++q){
    rhs_l[(r0+q)*33+bl]=acc[q];
    RHS[(r0+q)*B_TOT+b]=acc[q];
  }
  __syncthreads();
  #pragma unroll
  for (int q=0;q<16;++q) acc[q]=0.f;
  #pragma unroll 2
  for (int j=0;j<128;++j){
    float rv = rhs_l[j*33+bl];
    const float4* mp = (const float4*)&M1[j*128+r0];
    #pragma unroll
    for (int q4=0;q4<4;++q4){
      float4 mv = mp[q4];
      acc[4*q4+0]=fmaf(mv.x,rv,acc[4*q4+0]);
      acc[4*q4+1]=fmaf(mv.y,rv,acc[4*q4+1]);
      acc[4*q4+2]=fmaf(mv.z,rv,acc[4*q4+2]);
      acc[4*q4+3]=fmaf(mv.w,rv,acc[4*q4+3]);
    }
  }
  #pragma unroll
  for (int q=0;q<16;++q) TV[(r0+q)*B_TOT+b]=acc[q];
}

// ---- k_C: 128 threads per batch: build S(Dinv+K)S, Cholesky, solve, step ----
__global__ __launch_bounds__(128) void k_C(const float* __restrict__ K,
    const float* __restrict__ Kd, const float* __restrict__ h,
    const float* __restrict__ TV,
    float* __restrict__ S, float* __restrict__ LAM, float* __restrict__ GZ,
    float* __restrict__ Y, float* __restrict__ ALPHA){
  __shared__ __align__(16) float tri[TRI_SZ];
  __shared__ float scl_l[128];
  __shared__ float sh_t[128];
  __shared__ float red[2];
  const int t = threadIdx.x, b = blockIdx.x;
  const int lane = t&63, wid = t>>6;
  float s_t=S[t*B_TOT+b], l_t=LAM[t*B_TOT+b], g_t=GZ[t*B_TOT+b];
  float rp_t = g_t + s_t - h[t];
  float prod = s_t*l_t;
  #pragma unroll
  for (int o=32;o>0;o>>=1) prod += __shfl_xor(prod,o,64);
  if (lane==0) red[wid]=prod;
  __syncthreads();
  const float mu = (red[0]+red[1])*(1.f/128.f);
  float rc_t = s_t*l_t - 0.1f*mu;
  float di_t = fminf(s_t/l_t, 1e30f);
  float sc_t = rsqrtf(Kd[t]+di_t);
  scl_l[t]=sc_t;
  sh_t[t]=TV[t*B_TOT+b]*sc_t;
  __syncthreads();
  // build equilibrated triangle (unit diag): row sweep, 128-wide coalesced K reads
  #pragma unroll 4
  for (int i=0;i<128;++i){
    if (t<=i){
      tri[rowStart(i)+t] = (t==i)?1.f : K[i*128+t]*scl_l[i]*sc_t;
    }
  }
  __syncthreads();
  chol_factor_w2(tri, t, lane, wid);
  tri_solve_w2(tri, sh_t, t);
  float y = sh_t[t]*sc_t;
  float gd = di_t*y;                     // G dz = Dinv .* y (Woodbury identity)
  float ds = -rp_t - gd;
  float dl = (-rc_t - l_t*ds)/s_t;
  float ra = 1e9f;
  if (ds<0.f) ra = -s_t/ds;
  if (dl<0.f) ra = fminf(ra,-l_t/dl);
  #pragma unroll
  for (int o=32;o>0;o>>=1) ra = fminf(ra,__shfl_xor(ra,o,64));
  __syncthreads();                       // red[] reuse
  if (lane==0) red[wid]=ra;
  __syncthreads();
  const float alpha = fminf(1.0f, 0.99f*fminf(red[0],red[1]));
  S[t*B_TOT+b]   = s_t + alpha*ds;
  LAM[t*B_TOT+b] = l_t + alpha*dl;
  GZ[t*B_TOT+b]  = g_t + alpha*gd;
  Y[t*B_TOT+b]   = y;
  if (t==0) ALPHA[b]=alpha;
}

// ---- k_D: v = rhs - G^T y ; dz = Qi v ; z += a dz ; qz += a v ----
__global__ __launch_bounds__(256) void k_D(const float* __restrict__ G,
    const float* __restrict__ Qi, const float* __restrict__ RHS,
    const float* __restrict__ Y, const float* __restrict__ ALPHA,
    float* __restrict__ Zst, float* __restrict__ QZ){
  __shared__ float y_l[128*33];
  __shared__ float v_l[128*33];
  const int t=threadIdx.x, g=t>>5, bl=t&31;
  const int b = blockIdx.x*TB + bl;
  #pragma unroll
  for (int q=0;q<16;++q){
    int i=g+8*q;
    y_l[i*33+bl] = Y[i*B_TOT+b];
  }
  const float alpha = ALPHA[b];
  __syncthreads();
  const int r0=g*16;
  float acc[16];
  #pragma unroll
  for (int q=0;q<16;++q) acc[q]=RHS[(r0+q)*B_TOT+b];
  #pragma unroll 2
  for (int j=0;j<128;++j){
    float yv = y_l[j*33+bl];
    const float4* gp=(const float4*)&G[j*128+r0];
    #pragma unroll
    for (int q4=0;q4<4;++q4){
      float4 gv=gp[q4];
      acc[4*q4+0]=fmaf(-gv.x,yv,acc[4*q4+0]);
      acc[4*q4+1]=fmaf(-gv.y,yv,acc[4*q4+1]);
      acc[4*q4+2]=fmaf(-gv.z,yv,acc[4*q4+2]);
      acc[4*q4+3]=fmaf(-gv.w,yv,acc[4*q4+3]);
    }
  }
  #pragma unroll
  for (int q=0;q<16;++q){
    v_l[(r0+q)*33+bl]=acc[q];
    float* qp=&QZ[(r0+q)*B_TOT+b];
    *qp = *qp + alpha*acc[q];            // qz += a*v  (Q dz == v)
  }
  __syncthreads();
  #pragma unroll
  for (int q=0;q<16;++q) acc[q]=0.f;
  #pragma unroll 2
  for (int j=0;j<128;++j){
    float vv = v_l[j*33+bl];
    const float4* qp4=(const float4*)&Qi[j*128+r0];
    #pragma unroll
    for (int q4=0;q4<4;++q4){
      float4 qv=qp4[q4];
      acc[4*q4+0]=fmaf(qv.x,vv,acc[4*q4+0]);
      acc[4*q4+1]=fmaf(qv.y,vv,acc[4*q4+1]);
      acc[4*q4+2]=fmaf(qv.z,vv,acc[4*q4+2]);
      acc[4*q4+3]=fmaf(qv.w,vv,acc[4*q4+3]);
    }
  }
  #pragma unroll
  for (int q=0;q<16;++q){
    float* zp=&Zst[(r0+q)*B_TOT+b];
    *zp = *zp + alpha*acc[q];            // z += a*dz
  }
}

// out = log_softmax(Z.reshape(10, 32768), axis=1), Z stored n-major [i][B]
__global__ __launch_bounds__(1024) void k_logsoftmax(const float* __restrict__ Zst,
                                                     float* __restrict__ out){
  __shared__ float red[16];
  __shared__ float sval[2];
  const int r = blockIdx.x, t = threadIdx.x;
  float m = -1e30f;
  for (int k=t;k<32768;k+=1024){
    float v = Zst[(k&127)*B_TOT + r*256 + (k>>7)];
    m = fmaxf(m, v);
  }
  #pragma unroll
  for (int o=32;o>0;o>>=1) m = fmaxf(m, __shfl_down(m,o,64));
  if ((t&63)==0) red[t>>6] = m;
  __syncthreads();
  if (t==0){ float mm=red[0]; for (int w=1;w<16;++w) mm=fmaxf(mm,red[w]); sval[0]=mm; }
  __syncthreads();
  const float mx = sval[0];
  float s=0.f;
  for (int k=t;k<32768;k+=1024){
    float v = Zst[(k&127)*B_TOT + r*256 + (k>>7)];
    s += expf(v-mx);
  }
  #pragma unroll
  for (int o=32;o>0;o>>=1) s += __shfl_down(s,o,64);
  if ((t&63)==0) red[t>>6]=s;
  __syncthreads();
  if (t==0){ float ss=0.f; for (int w=0;w<16;++w) ss+=red[w]; sval[1]=logf(ss); }
  __syncthreads();
  const float lse = sval[1];
  for (int k=t;k<32768;k+=1024){
    float v = Zst[(k&127)*B_TOT + r*256 + (k>>7)];
    out[(size_t)r*32768+k] = v-mx-lse;
  }
}

extern "C" void kernel_launch(void* const* d_in, const int* in_sizes, int n_in,
                              void* d_out, int out_size, void* d_ws, size_t ws_size,
                              hipStream_t stream){
  // inputs: 0=x (unused), 1=Q[128x128], 2=p[2560x128], 3=G[128x128], 4=h[128], 5=m
  const float* Q = (const float*)d_in[1];
  const float* p = (const float*)d_in[2];
  const float* G = (const float*)d_in[3];
  const float* h = (const float*)d_in[4];
  float* ws  = (float*)d_ws;
  const int NE = 128*B_TOT;              // 327680
  float* Zst = ws;                       // [128][2560]
  float* Qi  = Zst + NE;                 // 16384
  float* M1  = Qi + 16384;               // 16384
  float* K   = M1 + 16384;               // 16384
  float* Kd  = K + 16384;                // 128
  float* ALPHA = Kd + 128;               // 2560
  float* Pt  = ALPHA + 2560;             // NE
  float* S   = Pt + NE;                  // NE
  float* LAM = S + NE;                   // NE
  float* GZ  = LAM + NE;                 // NE
  float* QZ  = GZ + NE;                  // NE
  float* RHS = QZ + NE;                  // NE
  float* TV  = RHS + NE;                 // NE
  float* Y   = TV + NE;                  // NE
  float* out = (float*)d_out;

  hipLaunchKernelGGL(k_prep, dim3(1), dim3(256), 0, stream, Q, G, Qi, M1);
  hipLaunchKernelGGL(k_kmat, dim3(64), dim3(256), 0, stream, G, M1, K, Kd);
  hipLaunchKernelGGL(k_init, dim3((NE+255)/256), dim3(256), 0, stream,
                     p, Pt, S, LAM, GZ, QZ, Zst);
  for (int it=0; it<20; ++it){
    hipLaunchKernelGGL(k_B, dim3(NB), dim3(256), 0, stream,
                       G, M1, Pt, h, S, LAM, GZ, QZ, RHS, TV);
    hipLaunchKernelGGL(k_C, dim3(B_TOT), dim3(128), 0, stream,
                       K, Kd, h, TV, S, LAM, GZ, Y, ALPHA);
    hipLaunchKernelGGL(k_D, dim3(NB), dim3(256), 0, stream,
                       G, Qi, RHS, Y, ALPHA, Zst, QZ);
  }
  hipLaunchKernelGGL(k_logsoftmax, dim3(10), dim3(1024), 0, stream, Zst, out);
}